// Round 5
// baseline (186.217 us; speedup 1.0000x reference)
//
#include <hip/hip_runtime.h>
#include <hip/hip_bf16.h>

// B=2, S=2048, D=1024, H=16, KVH=4, DK=64, R=16, groups=4, SCALING=1.0
// out (f32): (B,S,1024)

typedef __attribute__((ext_vector_type(8))) short short8;
typedef __attribute__((ext_vector_type(4))) float f32x4;
typedef __attribute__((ext_vector_type(16))) float f32x16;
typedef __attribute__((ext_vector_type(2))) unsigned int uint2v;
typedef __attribute__((ext_vector_type(4))) unsigned short ushort4v;

#define DEV static __device__ __forceinline__

DEV unsigned short f32_to_bf16(float f) {
  unsigned int u = __float_as_uint(f);
  u += 0x7FFFu + ((u >> 16) & 1u);   // RNE
  return (unsigned short)(u >> 16);
}

DEV unsigned int cvt_pk_bf16(float lo, float hi) {
  unsigned int r;
  asm("v_cvt_pk_bf16_f32 %0, %1, %2" : "=v"(r) : "v"(lo), "v"(hi));
  return r;
}

DEV short8 cvt8(f32x4 a, f32x4 b) {
  short8 r;
  r[0] = (short)f32_to_bf16(a[0]); r[1] = (short)f32_to_bf16(a[1]);
  r[2] = (short)f32_to_bf16(a[2]); r[3] = (short)f32_to_bf16(a[3]);
  r[4] = (short)f32_to_bf16(b[0]); r[5] = (short)f32_to_bf16(b[1]);
  r[6] = (short)f32_to_bf16(b[2]); r[7] = (short)f32_to_bf16(b[3]);
  return r;
}

// bijective XCD-chunk swizzle (nblk % 8 == 0)
DEV int xcd_chunk(int bid, int nblk) {
  const int chunk = nblk >> 3;
  return (bid & 7) * chunk + (bid >> 3);
}

// ---------- all four W_eff^T in one launch ----------
__global__ __launch_bounds__(256) void weff_all_kernel(
    const float* __restrict__ Wq, const float* __restrict__ Aq, const float* __restrict__ Bq, unsigned short* __restrict__ WqT,
    const float* __restrict__ Wk, const float* __restrict__ Ak, const float* __restrict__ Bk, unsigned short* __restrict__ WkT,
    const float* __restrict__ Wv, const float* __restrict__ Av, const float* __restrict__ Bv, unsigned short* __restrict__ WvT,
    const float* __restrict__ Wo, const float* __restrict__ Ao, const float* __restrict__ Bo, unsigned short* __restrict__ WoT) {
  __shared__ float tile[16][17];
  const int bx = blockIdx.x;
  const float *W, *A, *Bm; unsigned short* WT; int N, nb;
  if (bx < 64)       { W = Wq; A = Aq; Bm = Bq; WT = WqT; N = 1024; nb = bx; }
  else if (bx < 80)  { W = Wk; A = Ak; Bm = Bk; WT = WkT; N = 256;  nb = bx - 64; }
  else if (bx < 96)  { W = Wv; A = Av; Bm = Bv; WT = WvT; N = 256;  nb = bx - 80; }
  else               { W = Wo; A = Ao; Bm = Bo; WT = WoT; N = 1024; nb = bx - 96; }
  const int tx = threadIdx.x, ty = threadIdx.y;
  const int n0 = nb * 16, k0 = blockIdx.y * 16;
  const int n = n0 + tx, k = k0 + ty;
  float acc = W[(size_t)k * N + n];
#pragma unroll
  for (int r = 0; r < 16; ++r) acc += A[k * 16 + r] * Bm[(size_t)r * N + n];
  tile[ty][tx] = acc;
  __syncthreads();
  WT[(size_t)(n0 + ty) * 1024 + (k0 + tx)] = f32_to_bf16(tile[tx][ty]);
}

// ---------- LDS-staged GEMM core (unchanged from round 4) ----------
template <int OUTMODE, bool F32IN>
DEV void gemm_lds_core(const void* __restrict__ Xv, const unsigned short* __restrict__ WT,
                       void* __restrict__ Cv, int N, int m0b, int n0b,
                       unsigned short* lds) {
  constexpr int K = 1024, BK = 32, NT = K / BK;
  constexpr int RS = 40;
  constexpr int MATS = 128 * RS;
  const int tid = threadIdx.x;
  const int w = tid >> 6, l = tid & 63;
  const int lr = l & 15, lg = l >> 4;
  const int m0 = m0b + (w >> 1) * 64;
  const int n0 = n0b + (w & 1) * 64;
  const int wabase = (w >> 1) * 64;
  const int wbbase = (w & 1) * 64;

  const int srow = tid >> 1, shalf = tid & 1;
  const float* xf = (const float*)Xv + (size_t)(m0b + srow) * K + shalf * 16;
  const unsigned short* xh = (const unsigned short*)Xv + (size_t)(m0b + srow) * K + shalf * 16;
  const unsigned short* wsrc = WT + (size_t)(n0b + srow) * K + shalf * 16;

  f32x4 acc[4][4];
#pragma unroll
  for (int mm = 0; mm < 4; ++mm)
#pragma unroll
    for (int nn = 0; nn < 4; ++nn) acc[mm][nn] = f32x4{0.f, 0.f, 0.f, 0.f};

  f32x4 ar[4];
  short8 arh[2];
  short8 brh[2];

#define G_LOAD(T)                                                     \
  {                                                                   \
    const int off_ = (T) * BK;                                        \
    if (F32IN) {                                                      \
      ar[0] = *(const f32x4*)(xf + off_);                             \
      ar[1] = *(const f32x4*)(xf + off_ + 4);                         \
      ar[2] = *(const f32x4*)(xf + off_ + 8);                         \
      ar[3] = *(const f32x4*)(xf + off_ + 12);                        \
    } else {                                                          \
      arh[0] = *(const short8*)(xh + off_);                           \
      arh[1] = *(const short8*)(xh + off_ + 8);                       \
    }                                                                 \
    brh[0] = *(const short8*)(wsrc + off_);                           \
    brh[1] = *(const short8*)(wsrc + off_ + 8);                       \
  }

#define S_WRITE(BUF)                                                  \
  {                                                                   \
    unsigned short* Ab_ = lds + (BUF) * 2 * MATS;                     \
    unsigned short* Bb_ = Ab_ + MATS;                                 \
    unsigned short* ap_ = Ab_ + srow * RS + shalf * 16;               \
    if (F32IN) {                                                      \
      *(short8*)(ap_) = cvt8(ar[0], ar[1]);                           \
      *(short8*)(ap_ + 8) = cvt8(ar[2], ar[3]);                       \
    } else {                                                          \
      *(short8*)(ap_) = arh[0];                                       \
      *(short8*)(ap_ + 8) = arh[1];                                   \
    }                                                                 \
    unsigned short* bp_ = Bb_ + srow * RS + shalf * 16;               \
    *(short8*)(bp_) = brh[0];                                         \
    *(short8*)(bp_ + 8) = brh[1];                                     \
  }

  G_LOAD(0)
  S_WRITE(0)
  __syncthreads();
  int cur = 0;

  for (int t = 0; t < NT; ++t) {
    if (t + 1 < NT) G_LOAD(t + 1)

    const unsigned short* Ab = lds + cur * 2 * MATS;
    const unsigned short* Bb = Ab + MATS;
    short8 af[4], bfg[4];
#pragma unroll
    for (int mm = 0; mm < 4; ++mm)
      af[mm] = *(const short8*)(Ab + (wabase + mm * 16 + lr) * RS + lg * 8);
#pragma unroll
    for (int nn = 0; nn < 4; ++nn)
      bfg[nn] = *(const short8*)(Bb + (wbbase + nn * 16 + lr) * RS + lg * 8);

#pragma unroll
    for (int mm = 0; mm < 4; ++mm)
#pragma unroll
      for (int nn = 0; nn < 4; ++nn)
        acc[mm][nn] = __builtin_amdgcn_mfma_f32_16x16x32_bf16(af[mm], bfg[nn], acc[mm][nn], 0, 0, 0);

    if (t + 1 < NT) {
      S_WRITE(cur ^ 1)
      __syncthreads();
      cur ^= 1;
    }
  }
#undef G_LOAD
#undef S_WRITE

#pragma unroll
  for (int mm = 0; mm < 4; ++mm)
#pragma unroll
    for (int nn = 0; nn < 4; ++nn)
#pragma unroll
      for (int i = 0; i < 4; ++i) {
        const int row = m0 + mm * 16 + lg * 4 + i;
        const int col = n0 + nn * 16 + lr;
        const float v = acc[mm][nn][i];
        if (OUTMODE == 0) {
          ((unsigned short*)Cv)[(size_t)row * N + col] = f32_to_bf16(v);
        } else if (OUTMODE == 1) {
          ((float*)Cv)[(size_t)row * N + col] = v;
        } else if (OUTMODE == 2) {
          ((unsigned short*)Cv)[((size_t)((row >> 11) * 4 + (col >> 6)) * 64 + (col & 63)) * 2048 + (row & 2047)] = f32_to_bf16(v);
        } else {
          ((unsigned short*)Cv)[((size_t)((row >> 11) * 4 + (col >> 6)) * 2048 + (row & 2047)) * 64 + (col & 63)] = f32_to_bf16(v);
        }
      }
}

__global__ __launch_bounds__(256, 3) void qkv_kernel(
    const float* __restrict__ query, const float* __restrict__ key, const float* __restrict__ value,
    const unsigned short* __restrict__ WqT, const unsigned short* __restrict__ WkT, const unsigned short* __restrict__ WvT,
    unsigned short* __restrict__ Qw, unsigned short* __restrict__ Khm, unsigned short* __restrict__ Vtw) {
  __shared__ unsigned short lds[2 * 2 * 128 * 40];
  const int bx = blockIdx.x;
  if (bx < 256) {
    const int v = xcd_chunk(bx, 256);
    gemm_lds_core<0, true>(query, WqT, Qw, 1024, (v >> 3) * 128, (v & 7) * 128, lds);
  } else if (bx < 320) {
    const int v = xcd_chunk(bx - 256, 64);
    gemm_lds_core<3, true>(key, WkT, Khm, 256, (v >> 1) * 128, (v & 1) * 128, lds);
  } else {
    const int v = xcd_chunk(bx - 320, 64);
    gemm_lds_core<2, true>(value, WvT, Vtw, 256, (v >> 1) * 128, (v & 1) * 128, lds);
  }
}

__global__ __launch_bounds__(256, 3) void ogemm_kernel(const unsigned short* __restrict__ Xw,
                                                       const unsigned short* __restrict__ WoT,
                                                       float* __restrict__ out) {
  __shared__ unsigned short lds[2 * 2 * 128 * 40];
  const int v = xcd_chunk(blockIdx.x, 256);
  gemm_lds_core<1, false>(Xw, WoT, out, 1024, (v >> 3) * 128, (v & 7) * 128, lds);
}

// ---------- flash attention: 8-wave blocks, k round-robin, defer-max ----------
// Q [B][S][1024] bf16; Kh [(b*4+kv)*2048+s][64] bf16; Vt [(b*4+kv)*64+d][2048] bf16
// grid (64, 16, 2), block 512 (8 waves). Block owns q rows [qt*32, +32); wave w
// takes k-tiles kt = w, w+8, ... (64 k each); 8-partial LDS combine at end.
__global__ __launch_bounds__(512, 4) void attn4_kernel(const unsigned short* __restrict__ Q,
                                                       const unsigned short* __restrict__ Kh,
                                                       const unsigned short* __restrict__ Vt,
                                                       unsigned short* __restrict__ Xo) {
  const int l = threadIdx.x & 63, w = threadIdx.x >> 6;
  const int cq = l & 31, hi = l >> 5;
  const int qt = (int)(gridDim.x - 1 - blockIdx.x);   // longest-first
  const int h = blockIdx.y, b = blockIdx.z;
  const int kv = h >> 2;
  const int q0 = qt * 32;
  const int q = q0 + cq;
  const float LOG2E = 1.44269504f;
  const float slope2 = exp2f(-(float)(h + 1)) * LOG2E;
  const float qscale = 0.125f * LOG2E;

  const unsigned short* qp = Q + ((size_t)(b * 2048 + q)) * 1024 + h * 64 + hi * 8;
  short8 qf[4];
#pragma unroll
  for (int c = 0; c < 4; ++c) qf[c] = *(const short8*)(qp + c * 16);

  const unsigned short* Kb = Kh + ((size_t)(b * 4 + kv) * 2048) * 64 + hi * 8;
  const unsigned short* Vb = Vt + ((size_t)(b * 4 + kv) * 64 + cq) * 2048 + hi * 8;

  f32x16 oA, oB;
#pragma unroll
  for (int r = 0; r < 16; ++r) { oA[r] = 0.f; oB[r] = 0.f; }
  float mrun = -3e38f, lrun = 0.f;

  const float fhi = 4.0f * (float)hi;
  const int nkt = (q0 + 31) / 64 + 1;

  for (int kt = w; kt < nkt; kt += 8) {
    const int k0 = kt * 64;
    const unsigned short* kp = Kb + (size_t)(k0 + cq) * 64;

    f32x16 sA, sB;
#pragma unroll
    for (int r = 0; r < 16; ++r) { sA[r] = 0.f; sB[r] = 0.f; }
    __builtin_amdgcn_s_setprio(1);
#pragma unroll
    for (int c = 0; c < 4; ++c) {
      short8 kfa = *(const short8*)(kp + c * 16);
      short8 kfb = *(const short8*)(kp + 32 * 64 + c * 16);
      sA = __builtin_amdgcn_mfma_f32_32x32x16_bf16(kfa, qf[c], sA, 0, 0, 0);
      sB = __builtin_amdgcn_mfma_f32_32x32x16_bf16(kfb, qf[c], sB, 0, 0, 0);
    }
    __builtin_amdgcn_s_setprio(0);

    const float fhb   = fmaf(slope2, fhi, slope2 * (float)(k0 - q));
    const float fhb32 = fmaf(slope2, fhi, slope2 * (float)(k0 + 32 - q));
    const bool masked = (kt == nkt - 1);
    const int ikq4 = k0 - q + 4 * hi;
    float svA[16], svB[16];
#pragma unroll
    for (int r = 0; r < 16; ++r) {
      const int koffc = (r & 3) + 8 * (r >> 2);
      const float kf = (float)koffc;
      float va = fmaf(sA[r], qscale, fmaf(slope2, kf, fhb));
      float vb = fmaf(sB[r], qscale, fmaf(slope2, kf, fhb32));
      if (masked) {
        if (ikq4 + koffc > 0) va = -3e38f;
        if (ikq4 + koffc + 32 > 0) vb = -3e38f;
      }
      svA[r] = va; svB[r] = vb;
    }

    // tile max: 4 partial accumulators + cross-half shuffle
    float m0_ = fmaxf(svA[0], svB[0]), m1_ = fmaxf(svA[1], svB[1]);
    float m2_ = fmaxf(svA[2], svB[2]), m3_ = fmaxf(svA[3], svB[3]);
#pragma unroll
    for (int r = 4; r < 16; r += 4) {
      m0_ = fmaxf(m0_, fmaxf(svA[r], svB[r]));
      m1_ = fmaxf(m1_, fmaxf(svA[r + 1], svB[r + 1]));
      m2_ = fmaxf(m2_, fmaxf(svA[r + 2], svB[r + 2]));
      m3_ = fmaxf(m3_, fmaxf(svA[r + 3], svB[r + 3]));
    }
    float mx = fmaxf(fmaxf(m0_, m1_), fmaxf(m2_, m3_));
    mx = fmaxf(mx, __shfl_xor(mx, 32));

    // defer-max (T13): only rescale when the tile max grows past THR=8
    if (!__all(mx <= mrun + 8.0f)) {
      const float mnew = fmaxf(mrun, mx);
      const float fsc = exp2f(mrun - mnew);
      lrun *= fsc;
      mrun = mnew;
#pragma unroll
      for (int r = 0; r < 16; ++r) { oA[r] *= fsc; oB[r] *= fsc; }
    }

    float pA[16], pB[16];
    float l0_ = 0.f, l1_ = 0.f, l2_ = 0.f, l3_ = 0.f;
#pragma unroll
    for (int r = 0; r < 16; r += 4) {
      pA[r] = exp2f(svA[r] - mrun);     pB[r] = exp2f(svB[r] - mrun);
      pA[r + 1] = exp2f(svA[r + 1] - mrun); pB[r + 1] = exp2f(svB[r + 1] - mrun);
      pA[r + 2] = exp2f(svA[r + 2] - mrun); pB[r + 2] = exp2f(svB[r + 2] - mrun);
      pA[r + 3] = exp2f(svA[r + 3] - mrun); pB[r + 3] = exp2f(svB[r + 3] - mrun);
      l0_ += pA[r] + pB[r];
      l1_ += pA[r + 1] + pB[r + 1];
      l2_ += pA[r + 2] + pB[r + 2];
      l3_ += pA[r + 3] + pB[r + 3];
    }
    float ls = (l0_ + l1_) + (l2_ + l3_);
    ls += __shfl_xor(ls, 32);
    lrun += ls;

#define PV_HALF(PARR, KBASE)                                                          \
    {                                                                                 \
      _Pragma("unroll")                                                               \
      for (int g = 0; g < 2; ++g) {                                                   \
        unsigned int a0 = cvt_pk_bf16(PARR[g * 8 + 0], PARR[g * 8 + 1]);              \
        unsigned int b0 = cvt_pk_bf16(PARR[g * 8 + 4], PARR[g * 8 + 5]);              \
        unsigned int a1 = cvt_pk_bf16(PARR[g * 8 + 2], PARR[g * 8 + 3]);              \
        unsigned int b1 = cvt_pk_bf16(PARR[g * 8 + 6], PARR[g * 8 + 7]);              \
        uint2v r0 = __builtin_amdgcn_permlane32_swap(a0, b0, false, false);           \
        uint2v r1 = __builtin_amdgcn_permlane32_swap(a1, b1, false, false);           \
        union { unsigned int u[4]; short8 s; } pb_;                                   \
        pb_.u[0] = r0[0]; pb_.u[1] = r1[0]; pb_.u[2] = r0[1]; pb_.u[3] = r1[1];       \
        const unsigned short* vp = Vb + (KBASE) + g * 16;                             \
        short8 v0 = *(const short8*)(vp);                                             \
        short8 v1 = *(const short8*)(vp + (size_t)32 * 2048);                         \
        __builtin_amdgcn_s_setprio(1);                                                \
        oA = __builtin_amdgcn_mfma_f32_32x32x16_bf16(v0, pb_.s, oA, 0, 0, 0);         \
        oB = __builtin_amdgcn_mfma_f32_32x32x16_bf16(v1, pb_.s, oB, 0, 0, 0);         \
        __builtin_amdgcn_s_setprio(0);                                                \
      }                                                                               \
    }
    PV_HALF(pA, k0)
    PV_HALF(pB, k0 + 32)
#undef PV_HALF
  }

  // ---- 8-way cross-wave combine ----
  __shared__ float mbuf[8][32];
  __shared__ float lbuf[8][32];
  __shared__ float obuf[8][32][68];

  if (hi == 0) { mbuf[w][cq] = mrun; lbuf[w][cq] = lrun; }
#pragma unroll
  for (int g = 0; g < 4; ++g) {
    f32x4 t0 = {oA[g * 4 + 0], oA[g * 4 + 1], oA[g * 4 + 2], oA[g * 4 + 3]};
    f32x4 t1 = {oB[g * 4 + 0], oB[g * 4 + 1], oB[g * 4 + 2], oB[g * 4 + 3]};
    *(f32x4*)&obuf[w][cq][8 * g + 4 * hi] = t0;
    *(f32x4*)&obuf[w][cq][8 * g + 4 * hi + 32] = t1;
  }
  __syncthreads();

  // 512 threads: tq = row (32), 16 threads per row, 4 floats each
  const int tq = threadIdx.x >> 4;
  const int d0 = (threadIdx.x & 15) * 4;
  float mw[8];
#pragma unroll
  for (int w8 = 0; w8 < 8; ++w8) mw[w8] = mbuf[w8][tq];
  float mstar = fmaxf(fmaxf(fmaxf(mw[0], mw[1]), fmaxf(mw[2], mw[3])),
                      fmaxf(fmaxf(mw[4], mw[5]), fmaxf(mw[6], mw[7])));
  float sc[8], lstar = 0.f;
#pragma unroll
  for (int w8 = 0; w8 < 8; ++w8) {
    sc[w8] = exp2f(mw[w8] - mstar);
    lstar = fmaf(sc[w8], lbuf[w8][tq], lstar);
  }
  f32x4 av = {0.f, 0.f, 0.f, 0.f};
#pragma unroll
  for (int w8 = 0; w8 < 8; ++w8) {
    f32x4 u = *(const f32x4*)&obuf[w8][tq][d0];
#pragma unroll
    for (int j = 0; j < 4; ++j) av[j] = fmaf(sc[w8], u[j], av[j]);
  }
  const float rinv = __builtin_amdgcn_rcpf(lstar);
  ushort4v ov;
#pragma unroll
  for (int j = 0; j < 4; ++j) ov[j] = f32_to_bf16(av[j] * rinv);
  *(ushort4v*)(Xo + ((size_t)(b * 2048 + q0 + tq)) * 1024 + h * 64 + d0) = ov;
}

extern "C" void kernel_launch(void* const* d_in, const int* in_sizes, int n_in,
                              void* d_out, int out_size, void* d_ws, size_t ws_size,
                              hipStream_t stream) {
  const float* query = (const float*)d_in[0];
  const float* key   = (const float*)d_in[1];
  const float* value = (const float*)d_in[2];
  const float* Wq = (const float*)d_in[3];
  const float* Wk = (const float*)d_in[4];
  const float* Wv = (const float*)d_in[5];
  const float* Wo = (const float*)d_in[6];
  const float* Aq = (const float*)d_in[7];
  const float* Bq = (const float*)d_in[8];
  const float* Ak = (const float*)d_in[9];
  const float* Bk = (const float*)d_in[10];
  const float* Av = (const float*)d_in[11];
  const float* Bv = (const float*)d_in[12];
  const float* Ao = (const float*)d_in[13];
  const float* Bo = (const float*)d_in[14];

  unsigned short* ws  = (unsigned short*)d_ws;
  unsigned short* WqT = ws;                       // 1M elems
  unsigned short* WkT = WqT + 1024 * 1024;        // 256K
  unsigned short* WvT = WkT + 256 * 1024;         // 256K
  unsigned short* WoT = WvT + 256 * 1024;         // 1M
  unsigned short* Qw  = WoT + 1024 * 1024;        // 4M   [B][S][1024]
  unsigned short* Khm = Qw + 4096 * 1024;         // 1M   [(b*4+kv)*2048+s][64]
  unsigned short* Vtw = Khm + 4096 * 256;         // 1M   [(b*4+kv)*64+d][2048]
  unsigned short* Xw  = Vtw + 4096 * 256;         // 4M   attn out [B][S][1024]

  weff_all_kernel<<<dim3(160, 64), dim3(16, 16), 0, stream>>>(
      Wq, Aq, Bq, WqT, Wk, Ak, Bk, WkT, Wv, Av, Bv, WvT, Wo, Ao, Bo, WoT);

  qkv_kernel<<<384, 256, 0, stream>>>(query, key, value, WqT, WkT, WvT, Qw, Khm, Vtw);

  attn4_kernel<<<dim3(64, 16, 2), 512, 0, stream>>>(Qw, Khm, Vtw, Xw);

  ogemm_kernel<<<256, 256, 0, stream>>>(Xw, WoT, (float*)d_out);
}

// Round 6
// 184.225 us; speedup vs baseline: 1.0108x; 1.0108x over previous
//
#include <hip/hip_runtime.h>
#include <hip/hip_bf16.h>

// B=2, S=2048, D=1024, H=16, KVH=4, DK=64, R=16, groups=4, SCALING=1.0
// out (f32): (B,S,1024)

typedef __attribute__((ext_vector_type(8))) short short8;
typedef __attribute__((ext_vector_type(4))) float f32x4;
typedef __attribute__((ext_vector_type(16))) float f32x16;
typedef __attribute__((ext_vector_type(2))) unsigned int uint2v;

#define DEV static __device__ __forceinline__

DEV unsigned short f32_to_bf16(float f) {
  unsigned int u = __float_as_uint(f);
  u += 0x7FFFu + ((u >> 16) & 1u);   // RNE
  return (unsigned short)(u >> 16);
}

DEV unsigned int cvt_pk_bf16(float lo, float hi) {
  unsigned int r;
  asm("v_cvt_pk_bf16_f32 %0, %1, %2" : "=v"(r) : "v"(lo), "v"(hi));
  return r;
}

DEV short8 cvt8(f32x4 a, f32x4 b) {
  short8 r;
  r[0] = (short)f32_to_bf16(a[0]); r[1] = (short)f32_to_bf16(a[1]);
  r[2] = (short)f32_to_bf16(a[2]); r[3] = (short)f32_to_bf16(a[3]);
  r[4] = (short)f32_to_bf16(b[0]); r[5] = (short)f32_to_bf16(b[1]);
  r[6] = (short)f32_to_bf16(b[2]); r[7] = (short)f32_to_bf16(b[3]);
  return r;
}

// bijective XCD-chunk swizzle (nblk % 8 == 0)
DEV int xcd_chunk(int bid, int nblk) {
  const int chunk = nblk >> 3;
  return (bid & 7) * chunk + (bid >> 3);
}

// ---------- all four W_eff^T in one launch ----------
__global__ __launch_bounds__(256) void weff_all_kernel(
    const float* __restrict__ Wq, const float* __restrict__ Aq, const float* __restrict__ Bq, unsigned short* __restrict__ WqT,
    const float* __restrict__ Wk, const float* __restrict__ Ak, const float* __restrict__ Bk, unsigned short* __restrict__ WkT,
    const float* __restrict__ Wv, const float* __restrict__ Av, const float* __restrict__ Bv, unsigned short* __restrict__ WvT,
    const float* __restrict__ Wo, const float* __restrict__ Ao, const float* __restrict__ Bo, unsigned short* __restrict__ WoT) {
  __shared__ float tile[16][17];
  const int bx = blockIdx.x;
  const float *W, *A, *Bm; unsigned short* WT; int N, nb;
  if (bx < 64)       { W = Wq; A = Aq; Bm = Bq; WT = WqT; N = 1024; nb = bx; }
  else if (bx < 80)  { W = Wk; A = Ak; Bm = Bk; WT = WkT; N = 256;  nb = bx - 64; }
  else if (bx < 96)  { W = Wv; A = Av; Bm = Bv; WT = WvT; N = 256;  nb = bx - 80; }
  else               { W = Wo; A = Ao; Bm = Bo; WT = WoT; N = 1024; nb = bx - 96; }
  const int tx = threadIdx.x, ty = threadIdx.y;
  const int n0 = nb * 16, k0 = blockIdx.y * 16;
  const int n = n0 + tx, k = k0 + ty;
  float acc = W[(size_t)k * N + n];
#pragma unroll
  for (int r = 0; r < 16; ++r) acc += A[k * 16 + r] * Bm[(size_t)r * N + n];
  tile[ty][tx] = acc;
  __syncthreads();
  WT[(size_t)(n0 + ty) * 1024 + (k0 + tx)] = f32_to_bf16(tile[tx][ty]);
}

// ---------- LDS-staged GEMM core (unchanged) ----------
template <int OUTMODE, bool F32IN>
DEV void gemm_lds_core(const void* __restrict__ Xv, const unsigned short* __restrict__ WT,
                       void* __restrict__ Cv, int N, int m0b, int n0b,
                       unsigned short* lds) {
  constexpr int K = 1024, BK = 32, NT = K / BK;
  constexpr int RS = 40;
  constexpr int MATS = 128 * RS;
  const int tid = threadIdx.x;
  const int w = tid >> 6, l = tid & 63;
  const int lr = l & 15, lg = l >> 4;
  const int m0 = m0b + (w >> 1) * 64;
  const int n0 = n0b + (w & 1) * 64;
  const int wabase = (w >> 1) * 64;
  const int wbbase = (w & 1) * 64;

  const int srow = tid >> 1, shalf = tid & 1;
  const float* xf = (const float*)Xv + (size_t)(m0b + srow) * K + shalf * 16;
  const unsigned short* xh = (const unsigned short*)Xv + (size_t)(m0b + srow) * K + shalf * 16;
  const unsigned short* wsrc = WT + (size_t)(n0b + srow) * K + shalf * 16;

  f32x4 acc[4][4];
#pragma unroll
  for (int mm = 0; mm < 4; ++mm)
#pragma unroll
    for (int nn = 0; nn < 4; ++nn) acc[mm][nn] = f32x4{0.f, 0.f, 0.f, 0.f};

  f32x4 ar[4];
  short8 arh[2];
  short8 brh[2];

#define G_LOAD(T)                                                     \
  {                                                                   \
    const int off_ = (T) * BK;                                        \
    if (F32IN) {                                                      \
      ar[0] = *(const f32x4*)(xf + off_);                             \
      ar[1] = *(const f32x4*)(xf + off_ + 4);                         \
      ar[2] = *(const f32x4*)(xf + off_ + 8);                         \
      ar[3] = *(const f32x4*)(xf + off_ + 12);                        \
    } else {                                                          \
      arh[0] = *(const short8*)(xh + off_);                           \
      arh[1] = *(const short8*)(xh + off_ + 8);                       \
    }                                                                 \
    brh[0] = *(const short8*)(wsrc + off_);                           \
    brh[1] = *(const short8*)(wsrc + off_ + 8);                       \
  }

#define S_WRITE(BUF)                                                  \
  {                                                                   \
    unsigned short* Ab_ = lds + (BUF) * 2 * MATS;                     \
    unsigned short* Bb_ = Ab_ + MATS;                                 \
    unsigned short* ap_ = Ab_ + srow * RS + shalf * 16;               \
    if (F32IN) {                                                      \
      *(short8*)(ap_) = cvt8(ar[0], ar[1]);                           \
      *(short8*)(ap_ + 8) = cvt8(ar[2], ar[3]);                       \
    } else {                                                          \
      *(short8*)(ap_) = arh[0];                                       \
      *(short8*)(ap_ + 8) = arh[1];                                   \
    }                                                                 \
    unsigned short* bp_ = Bb_ + srow * RS + shalf * 16;               \
    *(short8*)(bp_) = brh[0];                                         \
    *(short8*)(bp_ + 8) = brh[1];                                     \
  }

  G_LOAD(0)
  S_WRITE(0)
  __syncthreads();
  int cur = 0;

  for (int t = 0; t < NT; ++t) {
    if (t + 1 < NT) G_LOAD(t + 1)

    const unsigned short* Ab = lds + cur * 2 * MATS;
    const unsigned short* Bb = Ab + MATS;
    short8 af[4], bfg[4];
#pragma unroll
    for (int mm = 0; mm < 4; ++mm)
      af[mm] = *(const short8*)(Ab + (wabase + mm * 16 + lr) * RS + lg * 8);
#pragma unroll
    for (int nn = 0; nn < 4; ++nn)
      bfg[nn] = *(const short8*)(Bb + (wbbase + nn * 16 + lr) * RS + lg * 8);

#pragma unroll
    for (int mm = 0; mm < 4; ++mm)
#pragma unroll
      for (int nn = 0; nn < 4; ++nn)
        acc[mm][nn] = __builtin_amdgcn_mfma_f32_16x16x32_bf16(af[mm], bfg[nn], acc[mm][nn], 0, 0, 0);

    if (t + 1 < NT) {
      S_WRITE(cur ^ 1)
      __syncthreads();
      cur ^= 1;
    }
  }
#undef G_LOAD
#undef S_WRITE

#pragma unroll
  for (int mm = 0; mm < 4; ++mm)
#pragma unroll
    for (int nn = 0; nn < 4; ++nn)
#pragma unroll
      for (int i = 0; i < 4; ++i) {
        const int row = m0 + mm * 16 + lg * 4 + i;
        const int col = n0 + nn * 16 + lr;
        const float v = acc[mm][nn][i];
        if (OUTMODE == 0) {
          ((unsigned short*)Cv)[(size_t)row * N + col] = f32_to_bf16(v);
        } else if (OUTMODE == 1) {
          ((float*)Cv)[(size_t)row * N + col] = v;
        } else if (OUTMODE == 2) {
          ((unsigned short*)Cv)[((size_t)((row >> 11) * 4 + (col >> 6)) * 64 + (col & 63)) * 2048 + (row & 2047)] = f32_to_bf16(v);
        } else {
          ((unsigned short*)Cv)[((size_t)((row >> 11) * 4 + (col >> 6)) * 2048 + (row & 2047)) * 64 + (col & 63)] = f32_to_bf16(v);
        }
      }
}

__global__ __launch_bounds__(256, 3) void qkv_kernel(
    const float* __restrict__ query, const float* __restrict__ key, const float* __restrict__ value,
    const unsigned short* __restrict__ WqT, const unsigned short* __restrict__ WkT, const unsigned short* __restrict__ WvT,
    unsigned short* __restrict__ Qw, unsigned short* __restrict__ Khm, unsigned short* __restrict__ Vtw) {
  __shared__ unsigned short lds[2 * 2 * 128 * 40];
  const int bx = blockIdx.x;
  if (bx < 256) {
    const int v = xcd_chunk(bx, 256);
    gemm_lds_core<0, true>(query, WqT, Qw, 1024, (v >> 3) * 128, (v & 7) * 128, lds);
  } else if (bx < 320) {
    const int v = xcd_chunk(bx - 256, 64);
    gemm_lds_core<3, true>(key, WkT, Khm, 256, (v >> 1) * 128, (v & 1) * 128, lds);
  } else {
    const int v = xcd_chunk(bx - 320, 64);
    gemm_lds_core<2, true>(value, WvT, Vtw, 256, (v >> 1) * 128, (v & 1) * 128, lds);
  }
}

__global__ __launch_bounds__(256, 3) void ogemm_kernel(const unsigned short* __restrict__ Xw,
                                                       const unsigned short* __restrict__ WoT,
                                                       float* __restrict__ out) {
  __shared__ unsigned short lds[2 * 2 * 128 * 40];
  const int v = xcd_chunk(blockIdx.x, 256);
  gemm_lds_core<1, false>(Xw, WoT, out, 1024, (v >> 3) * 128, (v & 7) * 128, lds);
}

// ---------- flash attention: 4-wave k-split + software-pipelined loads ----------
// Q [B][S][1024] bf16; Kh [(b*4+kv)*2048+s][64] bf16; Vt [(b*4+kv)*64+d][2048] bf16
// grid (64, 16, 2), block 256 (4 waves). Block owns q rows [qt*32, +32); wave w
// takes k-tiles kt = w, w+4, ...; V(kt) loaded at iter top, K(kt+4) prefetched
// after QK. __launch_bounds__(256,2): VGPR cap 256 so loads stay in flight.
__global__ __launch_bounds__(256, 2) void attn5_kernel(const unsigned short* __restrict__ Q,
                                                       const unsigned short* __restrict__ Kh,
                                                       const unsigned short* __restrict__ Vt,
                                                       unsigned short* __restrict__ Xo) {
  const int l = threadIdx.x & 63, w = threadIdx.x >> 6;
  const int cq = l & 31, hi = l >> 5;
  const int qt = (int)(gridDim.x - 1 - blockIdx.x);   // longest-first
  const int h = blockIdx.y, b = blockIdx.z;
  const int kv = h >> 2;
  const int q0 = qt * 32;
  const int q = q0 + cq;
  const float LOG2E = 1.44269504f;
  const float slope2 = exp2f(-(float)(h + 1)) * LOG2E;
  const float qscale = 0.125f * LOG2E;

  const unsigned short* qp = Q + ((size_t)(b * 2048 + q)) * 1024 + h * 64 + hi * 8;
  short8 qf[4];
#pragma unroll
  for (int c = 0; c < 4; ++c) qf[c] = *(const short8*)(qp + c * 16);

  const unsigned short* Kb = Kh + ((size_t)(b * 4 + kv) * 2048) * 64 + hi * 8;
  const unsigned short* Vb = Vt + ((size_t)(b * 4 + kv) * 64 + cq) * 2048 + hi * 8;

  f32x16 oA, oB;
#pragma unroll
  for (int r = 0; r < 16; ++r) { oA[r] = 0.f; oB[r] = 0.f; }
  float mrun = -3e38f, lrun = 0.f;

  const float fhi = 4.0f * (float)hi;
  const int nkt = (q0 + 31) / 64 + 1;

  // prologue: K fragments for this wave's first tile
  int kt = w;
  short8 kc[8];
  if (kt < nkt) {
    const unsigned short* kp = Kb + (size_t)(kt * 64 + cq) * 64;
#pragma unroll
    for (int c = 0; c < 4; ++c) {
      kc[c] = *(const short8*)(kp + c * 16);
      kc[4 + c] = *(const short8*)(kp + 32 * 64 + c * 16);
    }
  }

  for (; kt < nkt; kt += 4) {
    const int k0 = kt * 64;

    // V loads for THIS tile — issued first, consumed after softmax (~400 cyc away)
    const unsigned short* vpb = Vb + k0;
    short8 vc[8];
    vc[0] = *(const short8*)(vpb);
    vc[1] = *(const short8*)(vpb + 16);
    vc[2] = *(const short8*)(vpb + (size_t)32 * 2048);
    vc[3] = *(const short8*)(vpb + 16 + (size_t)32 * 2048);
    vc[4] = *(const short8*)(vpb + 32);
    vc[5] = *(const short8*)(vpb + 48);
    vc[6] = *(const short8*)(vpb + 32 + (size_t)32 * 2048);
    vc[7] = *(const short8*)(vpb + 48 + (size_t)32 * 2048);

    // QK^T on current K fragments
    f32x16 sA, sB;
#pragma unroll
    for (int r = 0; r < 16; ++r) { sA[r] = 0.f; sB[r] = 0.f; }
    __builtin_amdgcn_s_setprio(1);
#pragma unroll
    for (int c = 0; c < 4; ++c) {
      sA = __builtin_amdgcn_mfma_f32_32x32x16_bf16(kc[c], qf[c], sA, 0, 0, 0);
      sB = __builtin_amdgcn_mfma_f32_32x32x16_bf16(kc[4 + c], qf[c], sB, 0, 0, 0);
    }
    __builtin_amdgcn_s_setprio(0);

    // K prefetch for NEXT tile (kc dead now; kn coalesces into kc's regs)
    const int ktn = (kt + 4 < nkt) ? kt + 4 : kt;   // clamped, branch-free
    const unsigned short* kpn = Kb + (size_t)(ktn * 64 + cq) * 64;
    short8 kn[8];
#pragma unroll
    for (int c = 0; c < 4; ++c) {
      kn[c] = *(const short8*)(kpn + c * 16);
      kn[4 + c] = *(const short8*)(kpn + 32 * 64 + c * 16);
    }

    const float fhb   = fmaf(slope2, fhi, slope2 * (float)(k0 - q));
    const float fhb32 = fmaf(slope2, fhi, slope2 * (float)(k0 + 32 - q));
    const bool masked = (kt == nkt - 1);
    const int ikq4 = k0 - q + 4 * hi;
    float svA[16], svB[16];
#pragma unroll
    for (int r = 0; r < 16; ++r) {
      const int koffc = (r & 3) + 8 * (r >> 2);
      const float kf = (float)koffc;
      float va = fmaf(sA[r], qscale, fmaf(slope2, kf, fhb));
      float vb = fmaf(sB[r], qscale, fmaf(slope2, kf, fhb32));
      if (masked) {
        if (ikq4 + koffc > 0) va = -3e38f;
        if (ikq4 + koffc + 32 > 0) vb = -3e38f;
      }
      svA[r] = va; svB[r] = vb;
    }

    // tile max: 4 partial accumulators + cross-half shuffle
    float m0_ = fmaxf(svA[0], svB[0]), m1_ = fmaxf(svA[1], svB[1]);
    float m2_ = fmaxf(svA[2], svB[2]), m3_ = fmaxf(svA[3], svB[3]);
#pragma unroll
    for (int r = 4; r < 16; r += 4) {
      m0_ = fmaxf(m0_, fmaxf(svA[r], svB[r]));
      m1_ = fmaxf(m1_, fmaxf(svA[r + 1], svB[r + 1]));
      m2_ = fmaxf(m2_, fmaxf(svA[r + 2], svB[r + 2]));
      m3_ = fmaxf(m3_, fmaxf(svA[r + 3], svB[r + 3]));
    }
    float mx = fmaxf(fmaxf(m0_, m1_), fmaxf(m2_, m3_));
    mx = fmaxf(mx, __shfl_xor(mx, 32));

    // defer-max (T13)
    if (!__all(mx <= mrun + 8.0f)) {
      const float mnew = fmaxf(mrun, mx);
      const float fsc = exp2f(mrun - mnew);
      lrun *= fsc;
      mrun = mnew;
#pragma unroll
      for (int r = 0; r < 16; ++r) { oA[r] *= fsc; oB[r] *= fsc; }
    }

    float pA[16], pB[16];
    float l0_ = 0.f, l1_ = 0.f, l2_ = 0.f, l3_ = 0.f;
#pragma unroll
    for (int r = 0; r < 16; r += 4) {
      pA[r] = exp2f(svA[r] - mrun);     pB[r] = exp2f(svB[r] - mrun);
      pA[r + 1] = exp2f(svA[r + 1] - mrun); pB[r + 1] = exp2f(svB[r + 1] - mrun);
      pA[r + 2] = exp2f(svA[r + 2] - mrun); pB[r + 2] = exp2f(svB[r + 2] - mrun);
      pA[r + 3] = exp2f(svA[r + 3] - mrun); pB[r + 3] = exp2f(svB[r + 3] - mrun);
      l0_ += pA[r] + pB[r];
      l1_ += pA[r + 1] + pB[r + 1];
      l2_ += pA[r + 2] + pB[r + 2];
      l3_ += pA[r + 3] + pB[r + 3];
    }
    float ls = (l0_ + l1_) + (l2_ + l3_);
    ls += __shfl_xor(ls, 32);
    lrun += ls;

    // PV on preloaded V fragments
#define PV_HALF(PARR, VCP)                                                            \
    {                                                                                 \
      _Pragma("unroll")                                                               \
      for (int g = 0; g < 2; ++g) {                                                   \
        unsigned int a0 = cvt_pk_bf16(PARR[g * 8 + 0], PARR[g * 8 + 1]);              \
        unsigned int b0 = cvt_pk_bf16(PARR[g * 8 + 4], PARR[g * 8 + 5]);              \
        unsigned int a1 = cvt_pk_bf16(PARR[g * 8 + 2], PARR[g * 8 + 3]);              \
        unsigned int b1 = cvt_pk_bf16(PARR[g * 8 + 6], PARR[g * 8 + 7]);              \
        uint2v r0 = __builtin_amdgcn_permlane32_swap(a0, b0, false, false);           \
        uint2v r1 = __builtin_amdgcn_permlane32_swap(a1, b1, false, false);           \
        union { unsigned int u[4]; short8 s; } pb_;                                   \
        pb_.u[0] = r0[0]; pb_.u[1] = r1[0]; pb_.u[2] = r0[1]; pb_.u[3] = r1[1];       \
        __builtin_amdgcn_s_setprio(1);                                                \
        oA = __builtin_amdgcn_mfma_f32_32x32x16_bf16((VCP)[g], pb_.s, oA, 0, 0, 0);   \
        oB = __builtin_amdgcn_mfma_f32_32x32x16_bf16((VCP)[2 + g], pb_.s, oB, 0, 0, 0);\
        __builtin_amdgcn_s_setprio(0);                                                \
      }                                                                               \
    }
    PV_HALF(pA, &vc[0])
    PV_HALF(pB, &vc[4])
#undef PV_HALF

#pragma unroll
    for (int c = 0; c < 8; ++c) kc[c] = kn[c];
  }

  // ---- 4-way cross-wave combine ----
  __shared__ float mbuf[4][32];
  __shared__ float lbuf[4][32];
  __shared__ float obuf[4][32][68];

  if (hi == 0) { mbuf[w][cq] = mrun; lbuf[w][cq] = lrun; }
#pragma unroll
  for (int g = 0; g < 4; ++g) {
    f32x4 t0 = {oA[g * 4 + 0], oA[g * 4 + 1], oA[g * 4 + 2], oA[g * 4 + 3]};
    f32x4 t1 = {oB[g * 4 + 0], oB[g * 4 + 1], oB[g * 4 + 2], oB[g * 4 + 3]};
    *(f32x4*)&obuf[w][cq][8 * g + 4 * hi] = t0;
    *(f32x4*)&obuf[w][cq][8 * g + 4 * hi + 32] = t1;
  }
  __syncthreads();

  const int tq = threadIdx.x >> 3;
  const int d0 = (threadIdx.x & 7) * 8;
  float mw[4];
#pragma unroll
  for (int w4 = 0; w4 < 4; ++w4) mw[w4] = mbuf[w4][tq];
  float mstar = fmaxf(fmaxf(mw[0], mw[1]), fmaxf(mw[2], mw[3]));
  float sc[4], lstar = 0.f;
#pragma unroll
  for (int w4 = 0; w4 < 4; ++w4) {
    sc[w4] = exp2f(mw[w4] - mstar);
    lstar = fmaf(sc[w4], lbuf[w4][tq], lstar);
  }
  float av[8];
#pragma unroll
  for (int j = 0; j < 8; ++j) av[j] = 0.f;
#pragma unroll
  for (int w4 = 0; w4 < 4; ++w4) {
    f32x4 u0 = *(const f32x4*)&obuf[w4][tq][d0];
    f32x4 u1 = *(const f32x4*)&obuf[w4][tq][d0 + 4];
#pragma unroll
    for (int j = 0; j < 4; ++j) {
      av[j] = fmaf(sc[w4], u0[j], av[j]);
      av[j + 4] = fmaf(sc[w4], u1[j], av[j + 4]);
    }
  }
  const float rinv = __builtin_amdgcn_rcpf(lstar);
  short8 ov;
#pragma unroll
  for (int j = 0; j < 8; ++j) ov[j] = (short)f32_to_bf16(av[j] * rinv);
  *(short8*)(Xo + ((size_t)(b * 2048 + q0 + tq)) * 1024 + h * 64 + d0) = ov;
}

extern "C" void kernel_launch(void* const* d_in, const int* in_sizes, int n_in,
                              void* d_out, int out_size, void* d_ws, size_t ws_size,
                              hipStream_t stream) {
  const float* query = (const float*)d_in[0];
  const float* key   = (const float*)d_in[1];
  const float* value = (const float*)d_in[2];
  const float* Wq = (const float*)d_in[3];
  const float* Wk = (const float*)d_in[4];
  const float* Wv = (const float*)d_in[5];
  const float* Wo = (const float*)d_in[6];
  const float* Aq = (const float*)d_in[7];
  const float* Bq = (const float*)d_in[8];
  const float* Ak = (const float*)d_in[9];
  const float* Bk = (const float*)d_in[10];
  const float* Av = (const float*)d_in[11];
  const float* Bv = (const float*)d_in[12];
  const float* Ao = (const float*)d_in[13];
  const float* Bo = (const float*)d_in[14];

  unsigned short* ws  = (unsigned short*)d_ws;
  unsigned short* WqT = ws;                       // 1M elems
  unsigned short* WkT = WqT + 1024 * 1024;        // 256K
  unsigned short* WvT = WkT + 256 * 1024;         // 256K
  unsigned short* WoT = WvT + 256 * 1024;         // 1M
  unsigned short* Qw  = WoT + 1024 * 1024;        // 4M   [B][S][1024]
  unsigned short* Khm = Qw + 4096 * 1024;         // 1M   [(b*4+kv)*2048+s][64]
  unsigned short* Vtw = Khm + 4096 * 256;         // 1M   [(b*4+kv)*64+d][2048]
  unsigned short* Xw  = Vtw + 4096 * 256;         // 4M   attn out [B][S][1024]

  weff_all_kernel<<<dim3(160, 64), dim3(16, 16), 0, stream>>>(
      Wq, Aq, Bq, WqT, Wk, Ak, Bk, WkT, Wv, Av, Bv, WvT, Wo, Ao, Bo, WoT);

  qkv_kernel<<<384, 256, 0, stream>>>(query, key, value, WqT, WkT, WvT, Qw, Khm, Vtw);

  attn5_kernel<<<dim3(64, 16, 2), 256, 0, stream>>>(Qw, Khm, Vtw, Xw);

  ogemm_kernel<<<256, 256, 0, stream>>>(Xw, WoT, (float*)d_out);
}

// Round 7
// 156.122 us; speedup vs baseline: 1.1928x; 1.1800x over previous
//
#include <hip/hip_runtime.h>
#include <hip/hip_bf16.h>

// B=2, S=2048, D=1024, H=16, KVH=4, DK=64, R=16, groups=4, SCALING=1.0
// out (f32): (B,S,1024)

typedef __attribute__((ext_vector_type(8))) short short8;
typedef __attribute__((ext_vector_type(4))) float f32x4;
typedef __attribute__((ext_vector_type(16))) float f32x16;
typedef __attribute__((ext_vector_type(2))) unsigned int uint2v;
typedef __attribute__((ext_vector_type(4))) unsigned short ushort4v;

#define DEV static __device__ __forceinline__

DEV unsigned short f32_to_bf16(float f) {
  unsigned int u = __float_as_uint(f);
  u += 0x7FFFu + ((u >> 16) & 1u);   // RNE
  return (unsigned short)(u >> 16);
}

DEV unsigned int cvt_pk_bf16(float lo, float hi) {
  unsigned int r;
  asm("v_cvt_pk_bf16_f32 %0, %1, %2" : "=v"(r) : "v"(lo), "v"(hi));
  return r;
}

DEV short8 cvt8(f32x4 a, f32x4 b) {
  short8 r;
  r[0] = (short)f32_to_bf16(a[0]); r[1] = (short)f32_to_bf16(a[1]);
  r[2] = (short)f32_to_bf16(a[2]); r[3] = (short)f32_to_bf16(a[3]);
  r[4] = (short)f32_to_bf16(b[0]); r[5] = (short)f32_to_bf16(b[1]);
  r[6] = (short)f32_to_bf16(b[2]); r[7] = (short)f32_to_bf16(b[3]);
  return r;
}

// bijective XCD-chunk swizzle (nblk % 8 == 0)
DEV int xcd_chunk(int bid, int nblk) {
  const int chunk = nblk >> 3;
  return (bid & 7) * chunk + (bid >> 3);
}

// ---------- all four W_eff^T in one launch ----------
__global__ __launch_bounds__(256) void weff_all_kernel(
    const float* __restrict__ Wq, const float* __restrict__ Aq, const float* __restrict__ Bq, unsigned short* __restrict__ WqT,
    const float* __restrict__ Wk, const float* __restrict__ Ak, const float* __restrict__ Bk, unsigned short* __restrict__ WkT,
    const float* __restrict__ Wv, const float* __restrict__ Av, const float* __restrict__ Bv, unsigned short* __restrict__ WvT,
    const float* __restrict__ Wo, const float* __restrict__ Ao, const float* __restrict__ Bo, unsigned short* __restrict__ WoT) {
  __shared__ float tile[16][17];
  const int bx = blockIdx.x;
  const float *W, *A, *Bm; unsigned short* WT; int N, nb;
  if (bx < 64)       { W = Wq; A = Aq; Bm = Bq; WT = WqT; N = 1024; nb = bx; }
  else if (bx < 80)  { W = Wk; A = Ak; Bm = Bk; WT = WkT; N = 256;  nb = bx - 64; }
  else if (bx < 96)  { W = Wv; A = Av; Bm = Bv; WT = WvT; N = 256;  nb = bx - 80; }
  else               { W = Wo; A = Ao; Bm = Bo; WT = WoT; N = 1024; nb = bx - 96; }
  const int tx = threadIdx.x, ty = threadIdx.y;
  const int n0 = nb * 16, k0 = blockIdx.y * 16;
  const int n = n0 + tx, k = k0 + ty;
  float acc = W[(size_t)k * N + n];
#pragma unroll
  for (int r = 0; r < 16; ++r) acc += A[k * 16 + r] * Bm[(size_t)r * N + n];
  tile[ty][tx] = acc;
  __syncthreads();
  WT[(size_t)(n0 + ty) * 1024 + (k0 + tx)] = f32_to_bf16(tile[tx][ty]);
}

// ---------- LDS-staged GEMM core (unchanged) ----------
template <int OUTMODE, bool F32IN>
DEV void gemm_lds_core(const void* __restrict__ Xv, const unsigned short* __restrict__ WT,
                       void* __restrict__ Cv, int N, int m0b, int n0b,
                       unsigned short* lds) {
  constexpr int K = 1024, BK = 32, NT = K / BK;
  constexpr int RS = 40;
  constexpr int MATS = 128 * RS;
  const int tid = threadIdx.x;
  const int w = tid >> 6, l = tid & 63;
  const int lr = l & 15, lg = l >> 4;
  const int m0 = m0b + (w >> 1) * 64;
  const int n0 = n0b + (w & 1) * 64;
  const int wabase = (w >> 1) * 64;
  const int wbbase = (w & 1) * 64;

  const int srow = tid >> 1, shalf = tid & 1;
  const float* xf = (const float*)Xv + (size_t)(m0b + srow) * K + shalf * 16;
  const unsigned short* xh = (const unsigned short*)Xv + (size_t)(m0b + srow) * K + shalf * 16;
  const unsigned short* wsrc = WT + (size_t)(n0b + srow) * K + shalf * 16;

  f32x4 acc[4][4];
#pragma unroll
  for (int mm = 0; mm < 4; ++mm)
#pragma unroll
    for (int nn = 0; nn < 4; ++nn) acc[mm][nn] = f32x4{0.f, 0.f, 0.f, 0.f};

  f32x4 ar[4];
  short8 arh[2];
  short8 brh[2];

#define G_LOAD(T)                                                     \
  {                                                                   \
    const int off_ = (T) * BK;                                        \
    if (F32IN) {                                                      \
      ar[0] = *(const f32x4*)(xf + off_);                             \
      ar[1] = *(const f32x4*)(xf + off_ + 4);                         \
      ar[2] = *(const f32x4*)(xf + off_ + 8);                         \
      ar[3] = *(const f32x4*)(xf + off_ + 12);                        \
    } else {                                                          \
      arh[0] = *(const short8*)(xh + off_);                           \
      arh[1] = *(const short8*)(xh + off_ + 8);                       \
    }                                                                 \
    brh[0] = *(const short8*)(wsrc + off_);                           \
    brh[1] = *(const short8*)(wsrc + off_ + 8);                       \
  }

#define S_WRITE(BUF)                                                  \
  {                                                                   \
    unsigned short* Ab_ = lds + (BUF) * 2 * MATS;                     \
    unsigned short* Bb_ = Ab_ + MATS;                                 \
    unsigned short* ap_ = Ab_ + srow * RS + shalf * 16;               \
    if (F32IN) {                                                      \
      *(short8*)(ap_) = cvt8(ar[0], ar[1]);                           \
      *(short8*)(ap_ + 8) = cvt8(ar[2], ar[3]);                       \
    } else {                                                          \
      *(short8*)(ap_) = arh[0];                                       \
      *(short8*)(ap_ + 8) = arh[1];                                   \
    }                                                                 \
    unsigned short* bp_ = Bb_ + srow * RS + shalf * 16;               \
    *(short8*)(bp_) = brh[0];                                         \
    *(short8*)(bp_ + 8) = brh[1];                                     \
  }

  G_LOAD(0)
  S_WRITE(0)
  __syncthreads();
  int cur = 0;

  for (int t = 0; t < NT; ++t) {
    if (t + 1 < NT) G_LOAD(t + 1)

    const unsigned short* Ab = lds + cur * 2 * MATS;
    const unsigned short* Bb = Ab + MATS;
    short8 af[4], bfg[4];
#pragma unroll
    for (int mm = 0; mm < 4; ++mm)
      af[mm] = *(const short8*)(Ab + (wabase + mm * 16 + lr) * RS + lg * 8);
#pragma unroll
    for (int nn = 0; nn < 4; ++nn)
      bfg[nn] = *(const short8*)(Bb + (wbbase + nn * 16 + lr) * RS + lg * 8);

#pragma unroll
    for (int mm = 0; mm < 4; ++mm)
#pragma unroll
      for (int nn = 0; nn < 4; ++nn)
        acc[mm][nn] = __builtin_amdgcn_mfma_f32_16x16x32_bf16(af[mm], bfg[nn], acc[mm][nn], 0, 0, 0);

    if (t + 1 < NT) {
      S_WRITE(cur ^ 1)
      __syncthreads();
      cur ^= 1;
    }
  }
#undef G_LOAD
#undef S_WRITE

#pragma unroll
  for (int mm = 0; mm < 4; ++mm)
#pragma unroll
    for (int nn = 0; nn < 4; ++nn)
#pragma unroll
      for (int i = 0; i < 4; ++i) {
        const int row = m0 + mm * 16 + lg * 4 + i;
        const int col = n0 + nn * 16 + lr;
        const float v = acc[mm][nn][i];
        if (OUTMODE == 0) {
          ((unsigned short*)Cv)[(size_t)row * N + col] = f32_to_bf16(v);
        } else if (OUTMODE == 1) {
          ((float*)Cv)[(size_t)row * N + col] = v;
        } else if (OUTMODE == 2) {
          ((unsigned short*)Cv)[((size_t)((row >> 11) * 4 + (col >> 6)) * 64 + (col & 63)) * 2048 + (row & 2047)] = f32_to_bf16(v);
        } else {
          ((unsigned short*)Cv)[((size_t)((row >> 11) * 4 + (col >> 6)) * 2048 + (row & 2047)) * 64 + (col & 63)] = f32_to_bf16(v);
        }
      }
}

__global__ __launch_bounds__(256, 3) void qkv_kernel(
    const float* __restrict__ query, const float* __restrict__ key, const float* __restrict__ value,
    const unsigned short* __restrict__ WqT, const unsigned short* __restrict__ WkT, const unsigned short* __restrict__ WvT,
    unsigned short* __restrict__ Qw, unsigned short* __restrict__ Khm, unsigned short* __restrict__ Vtw) {
  __shared__ unsigned short lds[2 * 2 * 128 * 40];
  const int bx = blockIdx.x;
  if (bx < 256) {
    const int v = xcd_chunk(bx, 256);
    gemm_lds_core<0, true>(query, WqT, Qw, 1024, (v >> 3) * 128, (v & 7) * 128, lds);
  } else if (bx < 320) {
    const int v = xcd_chunk(bx - 256, 64);
    gemm_lds_core<3, true>(key, WkT, Khm, 256, (v >> 1) * 128, (v & 1) * 128, lds);
  } else {
    const int v = xcd_chunk(bx - 320, 64);
    gemm_lds_core<2, true>(value, WvT, Vtw, 256, (v >> 1) * 128, (v & 1) * 128, lds);
  }
}

__global__ __launch_bounds__(256, 3) void ogemm_kernel(const unsigned short* __restrict__ Xw,
                                                       const unsigned short* __restrict__ WoT,
                                                       float* __restrict__ out) {
  __shared__ unsigned short lds[2 * 2 * 128 * 40];
  const int v = xcd_chunk(blockIdx.x, 256);
  gemm_lds_core<1, false>(Xw, WoT, out, 1024, (v >> 3) * 128, (v & 7) * 128, lds);
}

// ---------- flash attention v6: K/V in LDS shared across 4 waves ----------
// Q [B][S][1024] bf16; Kh [(b*4+kv)*2048+s][64] bf16; Vt [(b*4+kv)*64+d][2048] bf16
// grid (16, 16, 2), block 256 (4 waves). Block owns 128 q-rows [qt*128, +128);
// wave w owns rows +w*32. K/V tiles (64 k) staged in LDS (XOR col swizzle,
// double-buffered, reg-staged, loads issued before compute), sequential k-loop,
// no cross-wave combine. Swapped-QK 32x32 MFMA, lane-local softmax, defer-max.
__global__ __launch_bounds__(256, 2) void attn6_kernel(const unsigned short* __restrict__ Q,
                                                       const unsigned short* __restrict__ Kh,
                                                       const unsigned short* __restrict__ Vt,
                                                       unsigned short* __restrict__ Xo) {
  __shared__ __align__(16) unsigned short kls[2][64 * 64];
  __shared__ __align__(16) unsigned short vls[2][64 * 64];

  const int tid = threadIdx.x;
  const int l = tid & 63, w = tid >> 6;
  const int cq = l & 31, hi = l >> 5;
  const int qt = (int)(gridDim.x - 1 - blockIdx.x);   // longest-first
  const int h = blockIdx.y, b = blockIdx.z;
  const int kv = h >> 2;
  const int qw0 = qt * 128 + w * 32;
  const int q = qw0 + cq;
  const float LOG2E = 1.44269504f;
  const float slope2 = exp2f(-(float)(h + 1)) * LOG2E;
  const float qscale = 0.125f * LOG2E;

  // Q fragments (held for whole loop)
  const unsigned short* qp = Q + ((size_t)(b * 2048 + q)) * 1024 + h * 64 + hi * 8;
  short8 qf[4];
#pragma unroll
  for (int c = 0; c < 4; ++c) qf[c] = *(const short8*)(qp + c * 16);

  const int nktb = 2 * qt + 2;                 // block k-tiles
  const int nktw = (qw0 + 31) / 64 + 1;        // this wave's k-tiles

  // staging: thread covers chunks j1=tid, j2=tid+256 of the 512x16B tile.
  // chunk j -> row=j>>3, col16=j&7; source col16 XOR'd by row&7 (swizzle),
  // LDS dest linear at j*8 elems. Read side applies the same XOR.
  const unsigned short* Kg = Kh + (size_t)(b * 4 + kv) * 2048 * 64;
  const unsigned short* Vg = Vt + (size_t)(b * 4 + kv) * 64 * 2048;
  const int j1 = tid, j2 = tid + 256;
  const int rk1 = j1 >> 3, rk2 = j2 >> 3;
  const int kc1 = (j1 & 7) ^ (rk1 & 7), kc2 = (j2 & 7) ^ (rk2 & 7);
  const unsigned short* ksrc1 = Kg + rk1 * 64 + kc1 * 8;
  const unsigned short* ksrc2 = Kg + rk2 * 64 + kc2 * 8;
  const unsigned short* vsrc1 = Vg + (size_t)rk1 * 2048 + kc1 * 8;
  const unsigned short* vsrc2 = Vg + (size_t)rk2 * 2048 + kc2 * 8;

  short8 skr1, skr2, svr1, svr2;
#define STG_LOAD(T)                                                  \
  {                                                                  \
    const int k0_ = (T) * 64;                                        \
    skr1 = *(const short8*)(ksrc1 + k0_ * 64);                       \
    skr2 = *(const short8*)(ksrc2 + k0_ * 64);                       \
    svr1 = *(const short8*)(vsrc1 + k0_);                            \
    svr2 = *(const short8*)(vsrc2 + k0_);                            \
  }
#define STG_WRITE(BUF)                                               \
  {                                                                  \
    *(short8*)(kls[BUF] + j1 * 8) = skr1;                            \
    *(short8*)(kls[BUF] + j2 * 8) = skr2;                            \
    *(short8*)(vls[BUF] + j1 * 8) = svr1;                            \
    *(short8*)(vls[BUF] + j2 * 8) = svr2;                            \
  }

  STG_LOAD(0)
  STG_WRITE(0)
  __syncthreads();
  int cur = 0;

  f32x16 oA, oB;
#pragma unroll
  for (int r = 0; r < 16; ++r) { oA[r] = 0.f; oB[r] = 0.f; }
  float mrun = -3e38f, lrun = 0.f;

  const float fhi = 4.0f * (float)hi;
  const int sx = cq & 7;           // read-side swizzle key (rows cq and cq+32 share it)
  const int rA = cq, rB = cq + 32;

  for (int kt = 0; kt < nktb; ++kt) {
    if (kt + 1 < nktb) STG_LOAD(kt + 1)

    if (kt < nktw) {
      const int k0 = kt * 64;
      const unsigned short* Kl = kls[cur];
      const unsigned short* Vl = vls[cur];

      f32x16 sA, sB;
#pragma unroll
      for (int r = 0; r < 16; ++r) { sA[r] = 0.f; sB[r] = 0.f; }
      __builtin_amdgcn_s_setprio(1);
#pragma unroll
      for (int c = 0; c < 4; ++c) {
        short8 ka = *(const short8*)(Kl + rA * 64 + (((c * 2 + hi) ^ sx) * 8));
        short8 kb = *(const short8*)(Kl + rB * 64 + (((c * 2 + hi) ^ sx) * 8));
        sA = __builtin_amdgcn_mfma_f32_32x32x16_bf16(ka, qf[c], sA, 0, 0, 0);
        sB = __builtin_amdgcn_mfma_f32_32x32x16_bf16(kb, qf[c], sB, 0, 0, 0);
      }
      __builtin_amdgcn_s_setprio(0);

      const float fhb   = fmaf(slope2, fhi, slope2 * (float)(k0 - q));
      const float fhb32 = fmaf(slope2, fhi, slope2 * (float)(k0 + 32 - q));
      const bool masked = (kt == nktw - 1);
      const int ikq4 = k0 - q + 4 * hi;
      float svA[16], svB[16];
#pragma unroll
      for (int r = 0; r < 16; ++r) {
        const int koffc = (r & 3) + 8 * (r >> 2);
        const float kf = (float)koffc;
        float va = fmaf(sA[r], qscale, fmaf(slope2, kf, fhb));
        float vb = fmaf(sB[r], qscale, fmaf(slope2, kf, fhb32));
        if (masked) {
          if (ikq4 + koffc > 0) va = -3e38f;
          if (ikq4 + koffc + 32 > 0) vb = -3e38f;
        }
        svA[r] = va; svB[r] = vb;
      }

      float m0_ = fmaxf(svA[0], svB[0]), m1_ = fmaxf(svA[1], svB[1]);
      float m2_ = fmaxf(svA[2], svB[2]), m3_ = fmaxf(svA[3], svB[3]);
#pragma unroll
      for (int r = 4; r < 16; r += 4) {
        m0_ = fmaxf(m0_, fmaxf(svA[r], svB[r]));
        m1_ = fmaxf(m1_, fmaxf(svA[r + 1], svB[r + 1]));
        m2_ = fmaxf(m2_, fmaxf(svA[r + 2], svB[r + 2]));
        m3_ = fmaxf(m3_, fmaxf(svA[r + 3], svB[r + 3]));
      }
      float mx = fmaxf(fmaxf(m0_, m1_), fmaxf(m2_, m3_));
      mx = fmaxf(mx, __shfl_xor(mx, 32));

      if (!__all(mx <= mrun + 8.0f)) {
        const float mnew = fmaxf(mrun, mx);
        const float fsc = exp2f(mrun - mnew);
        lrun *= fsc;
        mrun = mnew;
#pragma unroll
        for (int r = 0; r < 16; ++r) { oA[r] *= fsc; oB[r] *= fsc; }
      }

      float pA[16], pB[16];
      float l0_ = 0.f, l1_ = 0.f, l2_ = 0.f, l3_ = 0.f;
#pragma unroll
      for (int r = 0; r < 16; r += 4) {
        pA[r] = exp2f(svA[r] - mrun);         pB[r] = exp2f(svB[r] - mrun);
        pA[r + 1] = exp2f(svA[r + 1] - mrun); pB[r + 1] = exp2f(svB[r + 1] - mrun);
        pA[r + 2] = exp2f(svA[r + 2] - mrun); pB[r + 2] = exp2f(svB[r + 2] - mrun);
        pA[r + 3] = exp2f(svA[r + 3] - mrun); pB[r + 3] = exp2f(svB[r + 3] - mrun);
        l0_ += pA[r] + pB[r];
        l1_ += pA[r + 1] + pB[r + 1];
        l2_ += pA[r + 2] + pB[r + 2];
        l3_ += pA[r + 3] + pB[r + 3];
      }
      float ls = (l0_ + l1_) + (l2_ + l3_);
      ls += __shfl_xor(ls, 32);
      lrun += ls;

      // PV: V fragments from LDS (same swizzle); khalf 0 -> pA, 1 -> pB
#define PV_HALF(PARR, KHALF)                                                          \
      {                                                                               \
        _Pragma("unroll")                                                             \
        for (int g = 0; g < 2; ++g) {                                                 \
          unsigned int a0 = cvt_pk_bf16(PARR[g * 8 + 0], PARR[g * 8 + 1]);            \
          unsigned int b0 = cvt_pk_bf16(PARR[g * 8 + 4], PARR[g * 8 + 5]);            \
          unsigned int a1 = cvt_pk_bf16(PARR[g * 8 + 2], PARR[g * 8 + 3]);            \
          unsigned int b1 = cvt_pk_bf16(PARR[g * 8 + 6], PARR[g * 8 + 7]);            \
          uint2v r0 = __builtin_amdgcn_permlane32_swap(a0, b0, false, false);         \
          uint2v r1 = __builtin_amdgcn_permlane32_swap(a1, b1, false, false);         \
          union { unsigned int u[4]; short8 s; } pb_;                                 \
          pb_.u[0] = r0[0]; pb_.u[1] = r1[0]; pb_.u[2] = r0[1]; pb_.u[3] = r1[1];     \
          const int c16 = ((KHALF) * 4 + g * 2 + hi) ^ sx;                            \
          short8 v0 = *(const short8*)(Vl + rA * 64 + c16 * 8);                       \
          short8 v1 = *(const short8*)(Vl + rB * 64 + c16 * 8);                       \
          __builtin_amdgcn_s_setprio(1);                                              \
          oA = __builtin_amdgcn_mfma_f32_32x32x16_bf16(v0, pb_.s, oA, 0, 0, 0);       \
          oB = __builtin_amdgcn_mfma_f32_32x32x16_bf16(v1, pb_.s, oB, 0, 0, 0);       \
          __builtin_amdgcn_s_setprio(0);                                              \
        }                                                                             \
      }
      PV_HALF(pA, 0)
      PV_HALF(pB, 1)
#undef PV_HALF
    }

    if (kt + 1 < nktb) STG_WRITE(cur ^ 1)
    __syncthreads();
    cur ^= 1;
  }
#undef STG_LOAD
#undef STG_WRITE

  // direct per-wave epilogue (no cross-wave combine)
  const float rinv = __builtin_amdgcn_rcpf(lrun);
  unsigned short* op = Xo + ((size_t)(b * 2048 + q)) * 1024 + h * 64;
#pragma unroll
  for (int g = 0; g < 4; ++g) {
    const int d0 = g * 8 + 4 * hi;
    ushort4v t0, t1;
#pragma unroll
    for (int i = 0; i < 4; ++i) {
      t0[i] = f32_to_bf16(oA[g * 4 + i] * rinv);
      t1[i] = f32_to_bf16(oB[g * 4 + i] * rinv);
    }
    *(ushort4v*)(op + d0) = t0;
    *(ushort4v*)(op + 32 + d0) = t1;
  }
}

extern "C" void kernel_launch(void* const* d_in, const int* in_sizes, int n_in,
                              void* d_out, int out_size, void* d_ws, size_t ws_size,
                              hipStream_t stream) {
  const float* query = (const float*)d_in[0];
  const float* key   = (const float*)d_in[1];
  const float* value = (const float*)d_in[2];
  const float* Wq = (const float*)d_in[3];
  const float* Wk = (const float*)d_in[4];
  const float* Wv = (const float*)d_in[5];
  const float* Wo = (const float*)d_in[6];
  const float* Aq = (const float*)d_in[7];
  const float* Bq = (const float*)d_in[8];
  const float* Ak = (const float*)d_in[9];
  const float* Bk = (const float*)d_in[10];
  const float* Av = (const float*)d_in[11];
  const float* Bv = (const float*)d_in[12];
  const float* Ao = (const float*)d_in[13];
  const float* Bo = (const float*)d_in[14];

  unsigned short* ws  = (unsigned short*)d_ws;
  unsigned short* WqT = ws;                       // 1M elems
  unsigned short* WkT = WqT + 1024 * 1024;        // 256K
  unsigned short* WvT = WkT + 256 * 1024;         // 256K
  unsigned short* WoT = WvT + 256 * 1024;         // 1M
  unsigned short* Qw  = WoT + 1024 * 1024;        // 4M   [B][S][1024]
  unsigned short* Khm = Qw + 4096 * 1024;         // 1M   [(b*4+kv)*2048+s][64]
  unsigned short* Vtw = Khm + 4096 * 256;         // 1M   [(b*4+kv)*64+d][2048]
  unsigned short* Xw  = Vtw + 4096 * 256;         // 4M   attn out [B][S][1024]

  weff_all_kernel<<<dim3(160, 64), dim3(16, 16), 0, stream>>>(
      Wq, Aq, Bq, WqT, Wk, Ak, Bk, WkT, Wv, Av, Bv, WvT, Wo, Ao, Bo, WoT);

  qkv_kernel<<<384, 256, 0, stream>>>(query, key, value, WqT, WkT, WvT, Qw, Khm, Vtw);

  attn6_kernel<<<dim3(16, 16, 2), 256, 0, stream>>>(Qw, Khm, Vtw, Xw);

  ogemm_kernel<<<256, 256, 0, stream>>>(Xw, WoT, (float*)d_out);
}

// Round 8
// 123.932 us; speedup vs baseline: 1.5026x; 1.2597x over previous
//
#include <hip/hip_runtime.h>
#include <hip/hip_bf16.h>

// B=2, S=2048, D=1024, H=16, KVH=4, DK=64, R=16, groups=4, SCALING=1.0
// out (f32): (B,S,1024)

typedef __attribute__((ext_vector_type(8))) short short8;
typedef __attribute__((ext_vector_type(4))) float f32x4;
typedef __attribute__((ext_vector_type(16))) float f32x16;
typedef __attribute__((ext_vector_type(2))) unsigned int uint2v;
typedef __attribute__((ext_vector_type(4))) unsigned short ushort4v;

#define DEV static __device__ __forceinline__

DEV unsigned short f32_to_bf16(float f) {
  unsigned int u = __float_as_uint(f);
  u += 0x7FFFu + ((u >> 16) & 1u);   // RNE
  return (unsigned short)(u >> 16);
}

DEV unsigned int cvt_pk_bf16(float lo, float hi) {
  unsigned int r;
  asm("v_cvt_pk_bf16_f32 %0, %1, %2" : "=v"(r) : "v"(lo), "v"(hi));
  return r;
}

DEV float fexp2(float x) { return __builtin_amdgcn_exp2f(x); }

DEV short8 cvt8(f32x4 a, f32x4 b) {
  short8 r;
  r[0] = (short)f32_to_bf16(a[0]); r[1] = (short)f32_to_bf16(a[1]);
  r[2] = (short)f32_to_bf16(a[2]); r[3] = (short)f32_to_bf16(a[3]);
  r[4] = (short)f32_to_bf16(b[0]); r[5] = (short)f32_to_bf16(b[1]);
  r[6] = (short)f32_to_bf16(b[2]); r[7] = (short)f32_to_bf16(b[3]);
  return r;
}

// bijective XCD-chunk swizzle (nblk % 8 == 0)
DEV int xcd_chunk(int bid, int nblk) {
  const int chunk = nblk >> 3;
  return (bid & 7) * chunk + (bid >> 3);
}

// ---------- all four W_eff^T in one launch ----------
__global__ __launch_bounds__(256) void weff_all_kernel(
    const float* __restrict__ Wq, const float* __restrict__ Aq, const float* __restrict__ Bq, unsigned short* __restrict__ WqT,
    const float* __restrict__ Wk, const float* __restrict__ Ak, const float* __restrict__ Bk, unsigned short* __restrict__ WkT,
    const float* __restrict__ Wv, const float* __restrict__ Av, const float* __restrict__ Bv, unsigned short* __restrict__ WvT,
    const float* __restrict__ Wo, const float* __restrict__ Ao, const float* __restrict__ Bo, unsigned short* __restrict__ WoT) {
  __shared__ float tile[16][17];
  const int bx = blockIdx.x;
  const float *W, *A, *Bm; unsigned short* WT; int N, nb;
  if (bx < 64)       { W = Wq; A = Aq; Bm = Bq; WT = WqT; N = 1024; nb = bx; }
  else if (bx < 80)  { W = Wk; A = Ak; Bm = Bk; WT = WkT; N = 256;  nb = bx - 64; }
  else if (bx < 96)  { W = Wv; A = Av; Bm = Bv; WT = WvT; N = 256;  nb = bx - 80; }
  else               { W = Wo; A = Ao; Bm = Bo; WT = WoT; N = 1024; nb = bx - 96; }
  const int tx = threadIdx.x, ty = threadIdx.y;
  const int n0 = nb * 16, k0 = blockIdx.y * 16;
  const int n = n0 + tx, k = k0 + ty;
  float acc = W[(size_t)k * N + n];
#pragma unroll
  for (int r = 0; r < 16; ++r) acc += A[k * 16 + r] * Bm[(size_t)r * N + n];
  tile[ty][tx] = acc;
  __syncthreads();
  WT[(size_t)(n0 + ty) * 1024 + (k0 + tx)] = f32_to_bf16(tile[tx][ty]);
}

// ---------- LDS-staged GEMM core (unchanged) ----------
template <int OUTMODE, bool F32IN>
DEV void gemm_lds_core(const void* __restrict__ Xv, const unsigned short* __restrict__ WT,
                       void* __restrict__ Cv, int N, int m0b, int n0b,
                       unsigned short* lds) {
  constexpr int K = 1024, BK = 32, NT = K / BK;
  constexpr int RS = 40;
  constexpr int MATS = 128 * RS;
  const int tid = threadIdx.x;
  const int w = tid >> 6, l = tid & 63;
  const int lr = l & 15, lg = l >> 4;
  const int m0 = m0b + (w >> 1) * 64;
  const int n0 = n0b + (w & 1) * 64;
  const int wabase = (w >> 1) * 64;
  const int wbbase = (w & 1) * 64;

  const int srow = tid >> 1, shalf = tid & 1;
  const float* xf = (const float*)Xv + (size_t)(m0b + srow) * K + shalf * 16;
  const unsigned short* xh = (const unsigned short*)Xv + (size_t)(m0b + srow) * K + shalf * 16;
  const unsigned short* wsrc = WT + (size_t)(n0b + srow) * K + shalf * 16;

  f32x4 acc[4][4];
#pragma unroll
  for (int mm = 0; mm < 4; ++mm)
#pragma unroll
    for (int nn = 0; nn < 4; ++nn) acc[mm][nn] = f32x4{0.f, 0.f, 0.f, 0.f};

  f32x4 ar[4];
  short8 arh[2];
  short8 brh[2];

#define G_LOAD(T)                                                     \
  {                                                                   \
    const int off_ = (T) * BK;                                        \
    if (F32IN) {                                                      \
      ar[0] = *(const f32x4*)(xf + off_);                             \
      ar[1] = *(const f32x4*)(xf + off_ + 4);                         \
      ar[2] = *(const f32x4*)(xf + off_ + 8);                         \
      ar[3] = *(const f32x4*)(xf + off_ + 12);                        \
    } else {                                                          \
      arh[0] = *(const short8*)(xh + off_);                           \
      arh[1] = *(const short8*)(xh + off_ + 8);                       \
    }                                                                 \
    brh[0] = *(const short8*)(wsrc + off_);                           \
    brh[1] = *(const short8*)(wsrc + off_ + 8);                       \
  }

#define S_WRITE(BUF)                                                  \
  {                                                                   \
    unsigned short* Ab_ = lds + (BUF) * 2 * MATS;                     \
    unsigned short* Bb_ = Ab_ + MATS;                                 \
    unsigned short* ap_ = Ab_ + srow * RS + shalf * 16;               \
    if (F32IN) {                                                      \
      *(short8*)(ap_) = cvt8(ar[0], ar[1]);                           \
      *(short8*)(ap_ + 8) = cvt8(ar[2], ar[3]);                       \
    } else {                                                          \
      *(short8*)(ap_) = arh[0];                                       \
      *(short8*)(ap_ + 8) = arh[1];                                   \
    }                                                                 \
    unsigned short* bp_ = Bb_ + srow * RS + shalf * 16;               \
    *(short8*)(bp_) = brh[0];                                         \
    *(short8*)(bp_ + 8) = brh[1];                                     \
  }

  G_LOAD(0)
  S_WRITE(0)
  __syncthreads();
  int cur = 0;

  for (int t = 0; t < NT; ++t) {
    if (t + 1 < NT) G_LOAD(t + 1)

    const unsigned short* Ab = lds + cur * 2 * MATS;
    const unsigned short* Bb = Ab + MATS;
    short8 af[4], bfg[4];
#pragma unroll
    for (int mm = 0; mm < 4; ++mm)
      af[mm] = *(const short8*)(Ab + (wabase + mm * 16 + lr) * RS + lg * 8);
#pragma unroll
    for (int nn = 0; nn < 4; ++nn)
      bfg[nn] = *(const short8*)(Bb + (wbbase + nn * 16 + lr) * RS + lg * 8);

#pragma unroll
    for (int mm = 0; mm < 4; ++mm)
#pragma unroll
      for (int nn = 0; nn < 4; ++nn)
        acc[mm][nn] = __builtin_amdgcn_mfma_f32_16x16x32_bf16(af[mm], bfg[nn], acc[mm][nn], 0, 0, 0);

    if (t + 1 < NT) {
      S_WRITE(cur ^ 1)
      __syncthreads();
      cur ^= 1;
    }
  }
#undef G_LOAD
#undef S_WRITE

#pragma unroll
  for (int mm = 0; mm < 4; ++mm)
#pragma unroll
    for (int nn = 0; nn < 4; ++nn)
#pragma unroll
      for (int i = 0; i < 4; ++i) {
        const int row = m0 + mm * 16 + lg * 4 + i;
        const int col = n0 + nn * 16 + lr;
        const float v = acc[mm][nn][i];
        if (OUTMODE == 0) {
          ((unsigned short*)Cv)[(size_t)row * N + col] = f32_to_bf16(v);
        } else if (OUTMODE == 1) {
          ((float*)Cv)[(size_t)row * N + col] = v;
        } else if (OUTMODE == 2) {
          ((unsigned short*)Cv)[((size_t)((row >> 11) * 4 + (col >> 6)) * 64 + (col & 63)) * 2048 + (row & 2047)] = f32_to_bf16(v);
        } else {
          ((unsigned short*)Cv)[((size_t)((row >> 11) * 4 + (col >> 6)) * 2048 + (row & 2047)) * 64 + (col & 63)] = f32_to_bf16(v);
        }
      }
}

__global__ __launch_bounds__(256, 3) void qkv_kernel(
    const float* __restrict__ query, const float* __restrict__ key, const float* __restrict__ value,
    const unsigned short* __restrict__ WqT, const unsigned short* __restrict__ WkT, const unsigned short* __restrict__ WvT,
    unsigned short* __restrict__ Qw, unsigned short* __restrict__ Khm, unsigned short* __restrict__ Vtw) {
  __shared__ unsigned short lds[2 * 2 * 128 * 40];
  const int bx = blockIdx.x;
  if (bx < 256) {
    const int v = xcd_chunk(bx, 256);
    gemm_lds_core<0, true>(query, WqT, Qw, 1024, (v >> 3) * 128, (v & 7) * 128, lds);
  } else if (bx < 320) {
    const int v = xcd_chunk(bx - 256, 64);
    gemm_lds_core<3, true>(key, WkT, Khm, 256, (v >> 1) * 128, (v & 1) * 128, lds);
  } else {
    const int v = xcd_chunk(bx - 320, 64);
    gemm_lds_core<2, true>(value, WvT, Vtw, 256, (v >> 1) * 128, (v & 1) * 128, lds);
  }
}

__global__ __launch_bounds__(256, 3) void ogemm_kernel(const unsigned short* __restrict__ Xw,
                                                       const unsigned short* __restrict__ WoT,
                                                       float* __restrict__ out) {
  __shared__ unsigned short lds[2 * 2 * 128 * 40];
  const int v = xcd_chunk(blockIdx.x, 256);
  gemm_lds_core<1, false>(Xw, WoT, out, 1024, (v >> 3) * 128, (v & 7) * 128, lds);
}

// ---------- flash attention v7: LDS-shared K/V + work-balanced block pairing ----------
// 1D grid 512. Decode: half = bid>>8, p = bid&255, h = p&15, b = (p>>4)&1, j = p>>5.
// half 0 -> qt = 15-j (longest first); half 1 -> qt = j. Blocks bid and bid+256
// (which land on the same CU under round-robin dispatch) then carry qt and 15-qt:
// pair work = (2qt+2)+(2(15-qt)+2) = 36 iter-units = constant -> balanced makespan.
__global__ __launch_bounds__(256, 2) void attn7_kernel(const unsigned short* __restrict__ Q,
                                                       const unsigned short* __restrict__ Kh,
                                                       const unsigned short* __restrict__ Vt,
                                                       unsigned short* __restrict__ Xo) {
  __shared__ __align__(16) unsigned short kls[2][64 * 64];
  __shared__ __align__(16) unsigned short vls[2][64 * 64];

  const int tid = threadIdx.x;
  const int l = tid & 63, w = tid >> 6;
  const int cq = l & 31, hi = l >> 5;

  const int bid = blockIdx.x;
  const int half = bid >> 8, p = bid & 255;
  const int h = p & 15, b = (p >> 4) & 1, j = p >> 5;
  const int qt = half ? j : 15 - j;

  const int kv = h >> 2;
  const int qw0 = qt * 128 + w * 32;
  const int q = qw0 + cq;
  const float LOG2E = 1.44269504f;
  const float slope2 = fexp2(-(float)(h + 1)) * LOG2E;
  const float qscale = 0.125f * LOG2E;

  const unsigned short* qp = Q + ((size_t)(b * 2048 + q)) * 1024 + h * 64 + hi * 8;
  short8 qf[4];
#pragma unroll
  for (int c = 0; c < 4; ++c) qf[c] = *(const short8*)(qp + c * 16);

  const int nktb = 2 * qt + 2;                 // block k-tiles
  const int nktw = (qw0 + 31) / 64 + 1;        // this wave's k-tiles

  const unsigned short* Kg = Kh + (size_t)(b * 4 + kv) * 2048 * 64;
  const unsigned short* Vg = Vt + (size_t)(b * 4 + kv) * 64 * 2048;
  const int j1 = tid, j2 = tid + 256;
  const int rk1 = j1 >> 3, rk2 = j2 >> 3;
  const int kc1 = (j1 & 7) ^ (rk1 & 7), kc2 = (j2 & 7) ^ (rk2 & 7);
  const unsigned short* ksrc1 = Kg + rk1 * 64 + kc1 * 8;
  const unsigned short* ksrc2 = Kg + rk2 * 64 + kc2 * 8;
  const unsigned short* vsrc1 = Vg + (size_t)rk1 * 2048 + kc1 * 8;
  const unsigned short* vsrc2 = Vg + (size_t)rk2 * 2048 + kc2 * 8;

  short8 skr1, skr2, svr1, svr2;
#define STG_LOAD(T)                                                  \
  {                                                                  \
    const int k0_ = (T) * 64;                                        \
    skr1 = *(const short8*)(ksrc1 + k0_ * 64);                       \
    skr2 = *(const short8*)(ksrc2 + k0_ * 64);                       \
    svr1 = *(const short8*)(vsrc1 + k0_);                            \
    svr2 = *(const short8*)(vsrc2 + k0_);                            \
  }
#define STG_WRITE(BUF)                                               \
  {                                                                  \
    *(short8*)(kls[BUF] + j1 * 8) = skr1;                            \
    *(short8*)(kls[BUF] + j2 * 8) = skr2;                            \
    *(short8*)(vls[BUF] + j1 * 8) = svr1;                            \
    *(short8*)(vls[BUF] + j2 * 8) = svr2;                            \
  }

  STG_LOAD(0)
  STG_WRITE(0)
  __syncthreads();
  int cur = 0;

  f32x16 oA, oB;
#pragma unroll
  for (int r = 0; r < 16; ++r) { oA[r] = 0.f; oB[r] = 0.f; }
  float mrun = -3e38f, lrun = 0.f;

  const float fhi = 4.0f * (float)hi;
  const int sx = cq & 7;
  const int rA = cq, rB = cq + 32;

  for (int kt = 0; kt < nktb; ++kt) {
    if (kt + 1 < nktb) STG_LOAD(kt + 1)

    if (kt < nktw) {
      const int k0 = kt * 64;
      const unsigned short* Kl = kls[cur];
      const unsigned short* Vl = vls[cur];

      f32x16 sA, sB;
#pragma unroll
      for (int r = 0; r < 16; ++r) { sA[r] = 0.f; sB[r] = 0.f; }
      __builtin_amdgcn_s_setprio(1);
#pragma unroll
      for (int c = 0; c < 4; ++c) {
        short8 ka = *(const short8*)(Kl + rA * 64 + (((c * 2 + hi) ^ sx) * 8));
        short8 kb = *(const short8*)(Kl + rB * 64 + (((c * 2 + hi) ^ sx) * 8));
        sA = __builtin_amdgcn_mfma_f32_32x32x16_bf16(ka, qf[c], sA, 0, 0, 0);
        sB = __builtin_amdgcn_mfma_f32_32x32x16_bf16(kb, qf[c], sB, 0, 0, 0);
      }
      __builtin_amdgcn_s_setprio(0);

      const float fhb   = fmaf(slope2, fhi, slope2 * (float)(k0 - q));
      const float fhb32 = fmaf(slope2, fhi, slope2 * (float)(k0 + 32 - q));
      const bool masked = (kt == nktw - 1);
      const int ikq4 = k0 - q + 4 * hi;
      float svA[16], svB[16];
#pragma unroll
      for (int r = 0; r < 16; ++r) {
        const int koffc = (r & 3) + 8 * (r >> 2);
        const float kf = (float)koffc;
        float va = fmaf(sA[r], qscale, fmaf(slope2, kf, fhb));
        float vb = fmaf(sB[r], qscale, fmaf(slope2, kf, fhb32));
        if (masked) {
          if (ikq4 + koffc > 0) va = -3e38f;
          if (ikq4 + koffc + 32 > 0) vb = -3e38f;
        }
        svA[r] = va; svB[r] = vb;
      }

      float m0_ = fmaxf(svA[0], svB[0]), m1_ = fmaxf(svA[1], svB[1]);
      float m2_ = fmaxf(svA[2], svB[2]), m3_ = fmaxf(svA[3], svB[3]);
#pragma unroll
      for (int r = 4; r < 16; r += 4) {
        m0_ = fmaxf(m0_, fmaxf(svA[r], svB[r]));
        m1_ = fmaxf(m1_, fmaxf(svA[r + 1], svB[r + 1]));
        m2_ = fmaxf(m2_, fmaxf(svA[r + 2], svB[r + 2]));
        m3_ = fmaxf(m3_, fmaxf(svA[r + 3], svB[r + 3]));
      }
      float mx = fmaxf(fmaxf(m0_, m1_), fmaxf(m2_, m3_));
      mx = fmaxf(mx, __shfl_xor(mx, 32));

      if (!__all(mx <= mrun + 8.0f)) {
        const float mnew = fmaxf(mrun, mx);
        const float fsc = fexp2(mrun - mnew);
        lrun *= fsc;
        mrun = mnew;
#pragma unroll
        for (int r = 0; r < 16; ++r) { oA[r] *= fsc; oB[r] *= fsc; }
      }

      float pA[16], pB[16];
      float l0_ = 0.f, l1_ = 0.f, l2_ = 0.f, l3_ = 0.f;
#pragma unroll
      for (int r = 0; r < 16; r += 4) {
        pA[r] = fexp2(svA[r] - mrun);         pB[r] = fexp2(svB[r] - mrun);
        pA[r + 1] = fexp2(svA[r + 1] - mrun); pB[r + 1] = fexp2(svB[r + 1] - mrun);
        pA[r + 2] = fexp2(svA[r + 2] - mrun); pB[r + 2] = fexp2(svB[r + 2] - mrun);
        pA[r + 3] = fexp2(svA[r + 3] - mrun); pB[r + 3] = fexp2(svB[r + 3] - mrun);
        l0_ += pA[r] + pB[r];
        l1_ += pA[r + 1] + pB[r + 1];
        l2_ += pA[r + 2] + pB[r + 2];
        l3_ += pA[r + 3] + pB[r + 3];
      }
      float ls = (l0_ + l1_) + (l2_ + l3_);
      ls += __shfl_xor(ls, 32);
      lrun += ls;

#define PV_HALF(PARR, KHALF)                                                          \
      {                                                                               \
        _Pragma("unroll")                                                             \
        for (int g = 0; g < 2; ++g) {                                                 \
          unsigned int a0 = cvt_pk_bf16(PARR[g * 8 + 0], PARR[g * 8 + 1]);            \
          unsigned int b0 = cvt_pk_bf16(PARR[g * 8 + 4], PARR[g * 8 + 5]);            \
          unsigned int a1 = cvt_pk_bf16(PARR[g * 8 + 2], PARR[g * 8 + 3]);            \
          unsigned int b1 = cvt_pk_bf16(PARR[g * 8 + 6], PARR[g * 8 + 7]);            \
          uint2v r0 = __builtin_amdgcn_permlane32_swap(a0, b0, false, false);         \
          uint2v r1 = __builtin_amdgcn_permlane32_swap(a1, b1, false, false);         \
          union { unsigned int u[4]; short8 s; } pb_;                                 \
          pb_.u[0] = r0[0]; pb_.u[1] = r1[0]; pb_.u[2] = r0[1]; pb_.u[3] = r1[1];     \
          const int c16 = ((KHALF) * 4 + g * 2 + hi) ^ sx;                            \
          short8 v0 = *(const short8*)(Vl + rA * 64 + c16 * 8);                       \
          short8 v1 = *(const short8*)(Vl + rB * 64 + c16 * 8);                       \
          __builtin_amdgcn_s_setprio(1);                                              \
          oA = __builtin_amdgcn_mfma_f32_32x32x16_bf16(v0, pb_.s, oA, 0, 0, 0);       \
          oB = __builtin_amdgcn_mfma_f32_32x32x16_bf16(v1, pb_.s, oB, 0, 0, 0);       \
          __builtin_amdgcn_s_setprio(0);                                              \
        }                                                                             \
      }
      PV_HALF(pA, 0)
      PV_HALF(pB, 1)
#undef PV_HALF
    }

    if (kt + 1 < nktb) STG_WRITE(cur ^ 1)
    __syncthreads();
    cur ^= 1;
  }
#undef STG_LOAD
#undef STG_WRITE

  const float rinv = __builtin_amdgcn_rcpf(lrun);
  unsigned short* op = Xo + ((size_t)(b * 2048 + q)) * 1024 + h * 64;
#pragma unroll
  for (int g = 0; g < 4; ++g) {
    const int d0 = g * 8 + 4 * hi;
    ushort4v t0, t1;
#pragma unroll
    for (int i = 0; i < 4; ++i) {
      t0[i] = f32_to_bf16(oA[g * 4 + i] * rinv);
      t1[i] = f32_to_bf16(oB[g * 4 + i] * rinv);
    }
    *(ushort4v*)(op + d0) = t0;
    *(ushort4v*)(op + 32 + d0) = t1;
  }
}

extern "C" void kernel_launch(void* const* d_in, const int* in_sizes, int n_in,
                              void* d_out, int out_size, void* d_ws, size_t ws_size,
                              hipStream_t stream) {
  const float* query = (const float*)d_in[0];
  const float* key   = (const float*)d_in[1];
  const float* value = (const float*)d_in[2];
  const float* Wq = (const float*)d_in[3];
  const float* Wk = (const float*)d_in[4];
  const float* Wv = (const float*)d_in[5];
  const float* Wo = (const float*)d_in[6];
  const float* Aq = (const float*)d_in[7];
  const float* Bq = (const float*)d_in[8];
  const float* Ak = (const float*)d_in[9];
  const float* Bk = (const float*)d_in[10];
  const float* Av = (const float*)d_in[11];
  const float* Bv = (const float*)d_in[12];
  const float* Ao = (const float*)d_in[13];
  const float* Bo = (const float*)d_in[14];

  unsigned short* ws  = (unsigned short*)d_ws;
  unsigned short* WqT = ws;                       // 1M elems
  unsigned short* WkT = WqT + 1024 * 1024;        // 256K
  unsigned short* WvT = WkT + 256 * 1024;         // 256K
  unsigned short* WoT = WvT + 256 * 1024;         // 1M
  unsigned short* Qw  = WoT + 1024 * 1024;        // 4M   [B][S][1024]
  unsigned short* Khm = Qw + 4096 * 1024;         // 1M   [(b*4+kv)*2048+s][64]
  unsigned short* Vtw = Khm + 4096 * 256;         // 1M   [(b*4+kv)*64+d][2048]
  unsigned short* Xw  = Vtw + 4096 * 256;         // 4M   attn out [B][S][1024]

  weff_all_kernel<<<dim3(160, 64), dim3(16, 16), 0, stream>>>(
      Wq, Aq, Bq, WqT, Wk, Ak, Bk, WkT, Wv, Av, Bv, WvT, Wo, Ao, Bo, WoT);

  qkv_kernel<<<384, 256, 0, stream>>>(query, key, value, WqT, WkT, WvT, Qw, Khm, Vtw);

  attn7_kernel<<<512, 256, 0, stream>>>(Qw, Khm, Vtw, Xw);

  ogemm_kernel<<<256, 256, 0, stream>>>(Xw, WoT, (float*)d_out);
}

// Round 9
// 122.426 us; speedup vs baseline: 1.5211x; 1.0123x over previous
//
#include <hip/hip_runtime.h>
#include <hip/hip_bf16.h>

// B=2, S=2048, D=1024, H=16, KVH=4, DK=64, R=16, groups=4, SCALING=1.0
// out (f32): (B,S,1024)

typedef __attribute__((ext_vector_type(8))) short short8;
typedef __attribute__((ext_vector_type(4))) float f32x4;
typedef __attribute__((ext_vector_type(16))) float f32x16;
typedef __attribute__((ext_vector_type(2))) unsigned int uint2v;
typedef __attribute__((ext_vector_type(4))) unsigned short ushort4v;

#define DEV static __device__ __forceinline__

DEV unsigned short f32_to_bf16(float f) {
  unsigned int u = __float_as_uint(f);
  u += 0x7FFFu + ((u >> 16) & 1u);   // RNE
  return (unsigned short)(u >> 16);
}

DEV unsigned int cvt_pk_bf16(float lo, float hi) {
  unsigned int r;
  asm("v_cvt_pk_bf16_f32 %0, %1, %2" : "=v"(r) : "v"(lo), "v"(hi));
  return r;
}

DEV float fexp2(float x) { return __builtin_amdgcn_exp2f(x); }

DEV short8 cvt8(f32x4 a, f32x4 b) {
  short8 r;
  r[0] = (short)f32_to_bf16(a[0]); r[1] = (short)f32_to_bf16(a[1]);
  r[2] = (short)f32_to_bf16(a[2]); r[3] = (short)f32_to_bf16(a[3]);
  r[4] = (short)f32_to_bf16(b[0]); r[5] = (short)f32_to_bf16(b[1]);
  r[6] = (short)f32_to_bf16(b[2]); r[7] = (short)f32_to_bf16(b[3]);
  return r;
}

// bijective XCD-chunk swizzle (nblk % 8 == 0)
DEV int xcd_chunk(int bid, int nblk) {
  const int chunk = nblk >> 3;
  return (bid & 7) * chunk + (bid >> 3);
}

// ---------- all four W_eff^T in one launch ----------
__global__ __launch_bounds__(256) void weff_all_kernel(
    const float* __restrict__ Wq, const float* __restrict__ Aq, const float* __restrict__ Bq, unsigned short* __restrict__ WqT,
    const float* __restrict__ Wk, const float* __restrict__ Ak, const float* __restrict__ Bk, unsigned short* __restrict__ WkT,
    const float* __restrict__ Wv, const float* __restrict__ Av, const float* __restrict__ Bv, unsigned short* __restrict__ WvT,
    const float* __restrict__ Wo, const float* __restrict__ Ao, const float* __restrict__ Bo, unsigned short* __restrict__ WoT) {
  __shared__ float tile[16][17];
  const int bx = blockIdx.x;
  const float *W, *A, *Bm; unsigned short* WT; int N, nb;
  if (bx < 64)       { W = Wq; A = Aq; Bm = Bq; WT = WqT; N = 1024; nb = bx; }
  else if (bx < 80)  { W = Wk; A = Ak; Bm = Bk; WT = WkT; N = 256;  nb = bx - 64; }
  else if (bx < 96)  { W = Wv; A = Av; Bm = Bv; WT = WvT; N = 256;  nb = bx - 80; }
  else               { W = Wo; A = Ao; Bm = Bo; WT = WoT; N = 1024; nb = bx - 96; }
  const int tx = threadIdx.x, ty = threadIdx.y;
  const int n0 = nb * 16, k0 = blockIdx.y * 16;
  const int n = n0 + tx, k = k0 + ty;
  float acc = W[(size_t)k * N + n];
#pragma unroll
  for (int r = 0; r < 16; ++r) acc += A[k * 16 + r] * Bm[(size_t)r * N + n];
  tile[ty][tx] = acc;
  __syncthreads();
  WT[(size_t)(n0 + ty) * 1024 + (k0 + tx)] = f32_to_bf16(tile[tx][ty]);
}

// ---------- LDS-staged GEMM core: tile 128(M) x 64(N), BK=32 ----------
// 4 waves (2m x 2n); wave computes 64x32 (4x2 frags of 16x16x32 bf16 MFMA).
// A reg-staged with fused f32->bf16 cast (F32IN) into padded LDS (RS=40), B too.
// Double-buffered, 1 barrier per K-step. 30KB LDS -> 4 blocks/CU possible.
// OUTMODE: 0 bf16 row-major; 1 f32 row-major; 2 Vt [(b*4+kv)*64+d][2048];
//          3 K head-major [(b*4+kv)*2048+s][64]
template <int OUTMODE, bool F32IN>
DEV void gemm_lds_core(const void* __restrict__ Xv, const unsigned short* __restrict__ WT,
                       void* __restrict__ Cv, int N, int m0b, int n0b,
                       unsigned short* lds) {
  constexpr int K = 1024, BK = 32, NT = K / BK;
  constexpr int RS = 40;                       // padded row stride (bf16 elems)
  constexpr int ASZ = 128 * RS;                // A elems per buffer
  constexpr int BUF = ASZ + 64 * RS;           // total elems per buffer
  const int tid = threadIdx.x;
  const int w = tid >> 6, l = tid & 63;
  const int lr = l & 15, lg = l >> 4;
  const int m0 = m0b + (w >> 1) * 64;
  const int n0 = n0b + (w & 1) * 32;
  const int wabase = (w >> 1) * 64;
  const int wbbase = (w & 1) * 32;

  // A staging: thread covers (row = tid>>1, half = tid&1): 16 k-elems
  const int arow = tid >> 1, ahalf = tid & 1;
  const float* xf = (const float*)Xv + (size_t)(m0b + arow) * K + ahalf * 16;
  const unsigned short* xh = (const unsigned short*)Xv + (size_t)(m0b + arow) * K + ahalf * 16;
  // B staging: thread covers (row = tid>>2, q = tid&3): 8 k-elems
  const int brow = tid >> 2, bq = tid & 3;
  const unsigned short* wsrc = WT + (size_t)(n0b + brow) * K + bq * 8;

  f32x4 acc[4][2];
#pragma unroll
  for (int mm = 0; mm < 4; ++mm)
#pragma unroll
    for (int nn = 0; nn < 2; ++nn) acc[mm][nn] = f32x4{0.f, 0.f, 0.f, 0.f};

  f32x4 ar[4];
  short8 arh[2];
  short8 brh;

#define G_LOAD(T)                                                     \
  {                                                                   \
    const int off_ = (T) * BK;                                        \
    if (F32IN) {                                                      \
      ar[0] = *(const f32x4*)(xf + off_);                             \
      ar[1] = *(const f32x4*)(xf + off_ + 4);                         \
      ar[2] = *(const f32x4*)(xf + off_ + 8);                         \
      ar[3] = *(const f32x4*)(xf + off_ + 12);                        \
    } else {                                                          \
      arh[0] = *(const short8*)(xh + off_);                           \
      arh[1] = *(const short8*)(xh + off_ + 8);                       \
    }                                                                 \
    brh = *(const short8*)(wsrc + off_);                              \
  }

#define S_WRITE(B_)                                                   \
  {                                                                   \
    unsigned short* Ab_ = lds + (B_) * BUF;                           \
    unsigned short* ap_ = Ab_ + arow * RS + ahalf * 16;               \
    if (F32IN) {                                                      \
      *(short8*)(ap_) = cvt8(ar[0], ar[1]);                           \
      *(short8*)(ap_ + 8) = cvt8(ar[2], ar[3]);                       \
    } else {                                                          \
      *(short8*)(ap_) = arh[0];                                       \
      *(short8*)(ap_ + 8) = arh[1];                                   \
    }                                                                 \
    *(short8*)(Ab_ + ASZ + brow * RS + bq * 8) = brh;                 \
  }

  G_LOAD(0)
  S_WRITE(0)
  __syncthreads();
  int cur = 0;

  for (int t = 0; t < NT; ++t) {
    if (t + 1 < NT) G_LOAD(t + 1)

    const unsigned short* Ab = lds + cur * BUF;
    const unsigned short* Bb = Ab + ASZ;
    short8 af[4], bfg[2];
#pragma unroll
    for (int mm = 0; mm < 4; ++mm)
      af[mm] = *(const short8*)(Ab + (wabase + mm * 16 + lr) * RS + lg * 8);
#pragma unroll
    for (int nn = 0; nn < 2; ++nn)
      bfg[nn] = *(const short8*)(Bb + (wbbase + nn * 16 + lr) * RS + lg * 8);

#pragma unroll
    for (int mm = 0; mm < 4; ++mm)
#pragma unroll
      for (int nn = 0; nn < 2; ++nn)
        acc[mm][nn] = __builtin_amdgcn_mfma_f32_16x16x32_bf16(af[mm], bfg[nn], acc[mm][nn], 0, 0, 0);

    if (t + 1 < NT) {
      S_WRITE(cur ^ 1)
      __syncthreads();
      cur ^= 1;
    }
  }
#undef G_LOAD
#undef S_WRITE

#pragma unroll
  for (int mm = 0; mm < 4; ++mm)
#pragma unroll
    for (int nn = 0; nn < 2; ++nn)
#pragma unroll
      for (int i = 0; i < 4; ++i) {
        const int row = m0 + mm * 16 + lg * 4 + i;
        const int col = n0 + nn * 16 + lr;
        const float v = acc[mm][nn][i];
        if (OUTMODE == 0) {
          ((unsigned short*)Cv)[(size_t)row * N + col] = f32_to_bf16(v);
        } else if (OUTMODE == 1) {
          ((float*)Cv)[(size_t)row * N + col] = v;
        } else if (OUTMODE == 2) {
          ((unsigned short*)Cv)[((size_t)((row >> 11) * 4 + (col >> 6)) * 64 + (col & 63)) * 2048 + (row & 2047)] = f32_to_bf16(v);
        } else {
          ((unsigned short*)Cv)[((size_t)((row >> 11) * 4 + (col >> 6)) * 2048 + (row & 2047)) * 64 + (col & 63)] = f32_to_bf16(v);
        }
      }
}

// fused Q/K/V projections (+cast). Q: 512 blocks (32m x 16n), K/V: 128 each (32m x 4n).
__global__ __launch_bounds__(256, 4) void qkv_kernel(
    const float* __restrict__ query, const float* __restrict__ key, const float* __restrict__ value,
    const unsigned short* __restrict__ WqT, const unsigned short* __restrict__ WkT, const unsigned short* __restrict__ WvT,
    unsigned short* __restrict__ Qw, unsigned short* __restrict__ Khm, unsigned short* __restrict__ Vtw) {
  __shared__ unsigned short lds[2 * (128 * 40 + 64 * 40)];   // 30 KB
  const int bx = blockIdx.x;
  if (bx < 512) {
    const int v = xcd_chunk(bx, 512);
    gemm_lds_core<0, true>(query, WqT, Qw, 1024, (v >> 4) * 128, (v & 15) * 64, lds);
  } else if (bx < 640) {
    const int v = xcd_chunk(bx - 512, 128);
    gemm_lds_core<3, true>(key, WkT, Khm, 256, (v >> 2) * 128, (v & 3) * 64, lds);
  } else {
    const int v = xcd_chunk(bx - 640, 128);
    gemm_lds_core<2, true>(value, WvT, Vtw, 256, (v >> 2) * 128, (v & 3) * 64, lds);
  }
}

// O projection: bf16 in, f32 out. 512 blocks (32m x 16n).
__global__ __launch_bounds__(256, 4) void ogemm_kernel(const unsigned short* __restrict__ Xw,
                                                       const unsigned short* __restrict__ WoT,
                                                       float* __restrict__ out) {
  __shared__ unsigned short lds[2 * (128 * 40 + 64 * 40)];
  const int v = xcd_chunk(blockIdx.x, 512);
  gemm_lds_core<1, false>(Xw, WoT, out, 1024, (v >> 4) * 128, (v & 15) * 64, lds);
}

// ---------- flash attention v7 (unchanged): LDS-shared K/V + balanced pairing ----------
__global__ __launch_bounds__(256, 2) void attn7_kernel(const unsigned short* __restrict__ Q,
                                                       const unsigned short* __restrict__ Kh,
                                                       const unsigned short* __restrict__ Vt,
                                                       unsigned short* __restrict__ Xo) {
  __shared__ __align__(16) unsigned short kls[2][64 * 64];
  __shared__ __align__(16) unsigned short vls[2][64 * 64];

  const int tid = threadIdx.x;
  const int l = tid & 63, w = tid >> 6;
  const int cq = l & 31, hi = l >> 5;

  const int bid = blockIdx.x;
  const int half = bid >> 8, p = bid & 255;
  const int h = p & 15, b = (p >> 4) & 1, j = p >> 5;
  const int qt = half ? j : 15 - j;

  const int kv = h >> 2;
  const int qw0 = qt * 128 + w * 32;
  const int q = qw0 + cq;
  const float LOG2E = 1.44269504f;
  const float slope2 = fexp2(-(float)(h + 1)) * LOG2E;
  const float qscale = 0.125f * LOG2E;

  const unsigned short* qp = Q + ((size_t)(b * 2048 + q)) * 1024 + h * 64 + hi * 8;
  short8 qf[4];
#pragma unroll
  for (int c = 0; c < 4; ++c) qf[c] = *(const short8*)(qp + c * 16);

  const int nktb = 2 * qt + 2;
  const int nktw = (qw0 + 31) / 64 + 1;

  const unsigned short* Kg = Kh + (size_t)(b * 4 + kv) * 2048 * 64;
  const unsigned short* Vg = Vt + (size_t)(b * 4 + kv) * 64 * 2048;
  const int j1 = tid, j2 = tid + 256;
  const int rk1 = j1 >> 3, rk2 = j2 >> 3;
  const int kc1 = (j1 & 7) ^ (rk1 & 7), kc2 = (j2 & 7) ^ (rk2 & 7);
  const unsigned short* ksrc1 = Kg + rk1 * 64 + kc1 * 8;
  const unsigned short* ksrc2 = Kg + rk2 * 64 + kc2 * 8;
  const unsigned short* vsrc1 = Vg + (size_t)rk1 * 2048 + kc1 * 8;
  const unsigned short* vsrc2 = Vg + (size_t)rk2 * 2048 + kc2 * 8;

  short8 skr1, skr2, svr1, svr2;
#define STG_LOAD(T)                                                  \
  {                                                                  \
    const int k0_ = (T) * 64;                                        \
    skr1 = *(const short8*)(ksrc1 + k0_ * 64);                       \
    skr2 = *(const short8*)(ksrc2 + k0_ * 64);                       \
    svr1 = *(const short8*)(vsrc1 + k0_);                            \
    svr2 = *(const short8*)(vsrc2 + k0_);                            \
  }
#define STG_WRITE(BUF)                                               \
  {                                                                  \
    *(short8*)(kls[BUF] + j1 * 8) = skr1;                            \
    *(short8*)(kls[BUF] + j2 * 8) = skr2;                            \
    *(short8*)(vls[BUF] + j1 * 8) = svr1;                            \
    *(short8*)(vls[BUF] + j2 * 8) = svr2;                            \
  }

  STG_LOAD(0)
  STG_WRITE(0)
  __syncthreads();
  int cur = 0;

  f32x16 oA, oB;
#pragma unroll
  for (int r = 0; r < 16; ++r) { oA[r] = 0.f; oB[r] = 0.f; }
  float mrun = -3e38f, lrun = 0.f;

  const float fhi = 4.0f * (float)hi;
  const int sx = cq & 7;
  const int rA = cq, rB = cq + 32;

  for (int kt = 0; kt < nktb; ++kt) {
    if (kt + 1 < nktb) STG_LOAD(kt + 1)

    if (kt < nktw) {
      const int k0 = kt * 64;
      const unsigned short* Kl = kls[cur];
      const unsigned short* Vl = vls[cur];

      f32x16 sA, sB;
#pragma unroll
      for (int r = 0; r < 16; ++r) { sA[r] = 0.f; sB[r] = 0.f; }
      __builtin_amdgcn_s_setprio(1);
#pragma unroll
      for (int c = 0; c < 4; ++c) {
        short8 ka = *(const short8*)(Kl + rA * 64 + (((c * 2 + hi) ^ sx) * 8));
        short8 kb = *(const short8*)(Kl + rB * 64 + (((c * 2 + hi) ^ sx) * 8));
        sA = __builtin_amdgcn_mfma_f32_32x32x16_bf16(ka, qf[c], sA, 0, 0, 0);
        sB = __builtin_amdgcn_mfma_f32_32x32x16_bf16(kb, qf[c], sB, 0, 0, 0);
      }
      __builtin_amdgcn_s_setprio(0);

      const float fhb   = fmaf(slope2, fhi, slope2 * (float)(k0 - q));
      const float fhb32 = fmaf(slope2, fhi, slope2 * (float)(k0 + 32 - q));
      const bool masked = (kt == nktw - 1);
      const int ikq4 = k0 - q + 4 * hi;
      float svA[16], svB[16];
#pragma unroll
      for (int r = 0; r < 16; ++r) {
        const int koffc = (r & 3) + 8 * (r >> 2);
        const float kf = (float)koffc;
        float va = fmaf(sA[r], qscale, fmaf(slope2, kf, fhb));
        float vb = fmaf(sB[r], qscale, fmaf(slope2, kf, fhb32));
        if (masked) {
          if (ikq4 + koffc > 0) va = -3e38f;
          if (ikq4 + koffc + 32 > 0) vb = -3e38f;
        }
        svA[r] = va; svB[r] = vb;
      }

      float m0_ = fmaxf(svA[0], svB[0]), m1_ = fmaxf(svA[1], svB[1]);
      float m2_ = fmaxf(svA[2], svB[2]), m3_ = fmaxf(svA[3], svB[3]);
#pragma unroll
      for (int r = 4; r < 16; r += 4) {
        m0_ = fmaxf(m0_, fmaxf(svA[r], svB[r]));
        m1_ = fmaxf(m1_, fmaxf(svA[r + 1], svB[r + 1]));
        m2_ = fmaxf(m2_, fmaxf(svA[r + 2], svB[r + 2]));
        m3_ = fmaxf(m3_, fmaxf(svA[r + 3], svB[r + 3]));
      }
      float mx = fmaxf(fmaxf(m0_, m1_), fmaxf(m2_, m3_));
      mx = fmaxf(mx, __shfl_xor(mx, 32));

      if (!__all(mx <= mrun + 8.0f)) {
        const float mnew = fmaxf(mrun, mx);
        const float fsc = fexp2(mrun - mnew);
        lrun *= fsc;
        mrun = mnew;
#pragma unroll
        for (int r = 0; r < 16; ++r) { oA[r] *= fsc; oB[r] *= fsc; }
      }

      float pA[16], pB[16];
      float l0_ = 0.f, l1_ = 0.f, l2_ = 0.f, l3_ = 0.f;
#pragma unroll
      for (int r = 0; r < 16; r += 4) {
        pA[r] = fexp2(svA[r] - mrun);         pB[r] = fexp2(svB[r] - mrun);
        pA[r + 1] = fexp2(svA[r + 1] - mrun); pB[r + 1] = fexp2(svB[r + 1] - mrun);
        pA[r + 2] = fexp2(svA[r + 2] - mrun); pB[r + 2] = fexp2(svB[r + 2] - mrun);
        pA[r + 3] = fexp2(svA[r + 3] - mrun); pB[r + 3] = fexp2(svB[r + 3] - mrun);
        l0_ += pA[r] + pB[r];
        l1_ += pA[r + 1] + pB[r + 1];
        l2_ += pA[r + 2] + pB[r + 2];
        l3_ += pA[r + 3] + pB[r + 3];
      }
      float ls = (l0_ + l1_) + (l2_ + l3_);
      ls += __shfl_xor(ls, 32);
      lrun += ls;

#define PV_HALF(PARR, KHALF)                                                          \
      {                                                                               \
        _Pragma("unroll")                                                             \
        for (int g = 0; g < 2; ++g) {                                                 \
          unsigned int a0 = cvt_pk_bf16(PARR[g * 8 + 0], PARR[g * 8 + 1]);            \
          unsigned int b0 = cvt_pk_bf16(PARR[g * 8 + 4], PARR[g * 8 + 5]);            \
          unsigned int a1 = cvt_pk_bf16(PARR[g * 8 + 2], PARR[g * 8 + 3]);            \
          unsigned int b1 = cvt_pk_bf16(PARR[g * 8 + 6], PARR[g * 8 + 7]);            \
          uint2v r0 = __builtin_amdgcn_permlane32_swap(a0, b0, false, false);         \
          uint2v r1 = __builtin_amdgcn_permlane32_swap(a1, b1, false, false);         \
          union { unsigned int u[4]; short8 s; } pb_;                                 \
          pb_.u[0] = r0[0]; pb_.u[1] = r1[0]; pb_.u[2] = r0[1]; pb_.u[3] = r1[1];     \
          const int c16 = ((KHALF) * 4 + g * 2 + hi) ^ sx;                            \
          short8 v0 = *(const short8*)(Vl + rA * 64 + c16 * 8);                       \
          short8 v1 = *(const short8*)(Vl + rB * 64 + c16 * 8);                       \
          __builtin_amdgcn_s_setprio(1);                                              \
          oA = __builtin_amdgcn_mfma_f32_32x32x16_bf16(v0, pb_.s, oA, 0, 0, 0);       \
          oB = __builtin_amdgcn_mfma_f32_32x32x16_bf16(v1, pb_.s, oB, 0, 0, 0);       \
          __builtin_amdgcn_s_setprio(0);                                              \
        }                                                                             \
      }
      PV_HALF(pA, 0)
      PV_HALF(pB, 1)
#undef PV_HALF
    }

    if (kt + 1 < nktb) STG_WRITE(cur ^ 1)
    __syncthreads();
    cur ^= 1;
  }
#undef STG_LOAD
#undef STG_WRITE

  const float rinv = __builtin_amdgcn_rcpf(lrun);
  unsigned short* op = Xo + ((size_t)(b * 2048 + q)) * 1024 + h * 64;
#pragma unroll
  for (int g = 0; g < 4; ++g) {
    const int d0 = g * 8 + 4 * hi;
    ushort4v t0, t1;
#pragma unroll
    for (int i = 0; i < 4; ++i) {
      t0[i] = f32_to_bf16(oA[g * 4 + i] * rinv);
      t1[i] = f32_to_bf16(oB[g * 4 + i] * rinv);
    }
    *(ushort4v*)(op + d0) = t0;
    *(ushort4v*)(op + 32 + d0) = t1;
  }
}

extern "C" void kernel_launch(void* const* d_in, const int* in_sizes, int n_in,
                              void* d_out, int out_size, void* d_ws, size_t ws_size,
                              hipStream_t stream) {
  const float* query = (const float*)d_in[0];
  const float* key   = (const float*)d_in[1];
  const float* value = (const float*)d_in[2];
  const float* Wq = (const float*)d_in[3];
  const float* Wk = (const float*)d_in[4];
  const float* Wv = (const float*)d_in[5];
  const float* Wo = (const float*)d_in[6];
  const float* Aq = (const float*)d_in[7];
  const float* Bq = (const float*)d_in[8];
  const float* Ak = (const float*)d_in[9];
  const float* Bk = (const float*)d_in[10];
  const float* Av = (const float*)d_in[11];
  const float* Bv = (const float*)d_in[12];
  const float* Ao = (const float*)d_in[13];
  const float* Bo = (const float*)d_in[14];

  unsigned short* ws  = (unsigned short*)d_ws;
  unsigned short* WqT = ws;                       // 1M elems
  unsigned short* WkT = WqT + 1024 * 1024;        // 256K
  unsigned short* WvT = WkT + 256 * 1024;         // 256K
  unsigned short* WoT = WvT + 256 * 1024;         // 1M
  unsigned short* Qw  = WoT + 1024 * 1024;        // 4M   [B][S][1024]
  unsigned short* Khm = Qw + 4096 * 1024;         // 1M   [(b*4+kv)*2048+s][64]
  unsigned short* Vtw = Khm + 4096 * 256;         // 1M   [(b*4+kv)*64+d][2048]
  unsigned short* Xw  = Vtw + 4096 * 256;         // 4M   attn out [B][S][1024]

  weff_all_kernel<<<dim3(160, 64), dim3(16, 16), 0, stream>>>(
      Wq, Aq, Bq, WqT, Wk, Ak, Bk, WkT, Wv, Av, Bv, WvT, Wo, Ao, Bo, WoT);

  qkv_kernel<<<768, 256, 0, stream>>>(query, key, value, WqT, WkT, WvT, Qw, Khm, Vtw);

  attn7_kernel<<<512, 256, 0, stream>>>(Qw, Khm, Vtw, Xw);

  ogemm_kernel<<<512, 256, 0, stream>>>(Xw, WoT, (float*)d_out);
}

// Round 10
// 113.705 us; speedup vs baseline: 1.6377x; 1.0767x over previous
//
#include <hip/hip_runtime.h>
#include <hip/hip_bf16.h>

// B=2, S=2048, D=1024, H=16, KVH=4, DK=64, R=16, groups=4, SCALING=1.0
// out (f32): (B,S,1024)

typedef __attribute__((ext_vector_type(8))) short short8;
typedef __attribute__((ext_vector_type(4))) float f32x4;
typedef __attribute__((ext_vector_type(16))) float f32x16;
typedef __attribute__((ext_vector_type(2))) unsigned int uint2v;
typedef __attribute__((ext_vector_type(4))) unsigned short ushort4v;

#define DEV static __device__ __forceinline__

DEV unsigned short f32_to_bf16(float f) {
  unsigned int u = __float_as_uint(f);
  u += 0x7FFFu + ((u >> 16) & 1u);   // RNE
  return (unsigned short)(u >> 16);
}

DEV unsigned int cvt_pk_bf16(float lo, float hi) {
  unsigned int r;
  asm("v_cvt_pk_bf16_f32 %0, %1, %2" : "=v"(r) : "v"(lo), "v"(hi));
  return r;
}

DEV float fexp2(float x) { return __builtin_amdgcn_exp2f(x); }

DEV short8 cvt8(f32x4 a, f32x4 b) {
  short8 r;
  r[0] = (short)f32_to_bf16(a[0]); r[1] = (short)f32_to_bf16(a[1]);
  r[2] = (short)f32_to_bf16(a[2]); r[3] = (short)f32_to_bf16(a[3]);
  r[4] = (short)f32_to_bf16(b[0]); r[5] = (short)f32_to_bf16(b[1]);
  r[6] = (short)f32_to_bf16(b[2]); r[7] = (short)f32_to_bf16(b[3]);
  return r;
}

// async global->LDS, 16B per lane; lds base must be wave-uniform (HW adds lane*16)
DEV void gld16(const unsigned short* g, unsigned short* l) {
  __builtin_amdgcn_global_load_lds(
      (const __attribute__((address_space(1))) void*)g,
      (__attribute__((address_space(3))) void*)l,
      16, 0, 0);
}

// bijective XCD-chunk swizzle (nblk % 8 == 0)
DEV int xcd_chunk(int bid, int nblk) {
  const int chunk = nblk >> 3;
  return (bid & 7) * chunk + (bid >> 3);
}

// ---------- all four W_eff^T in one launch ----------
__global__ __launch_bounds__(256) void weff_all_kernel(
    const float* __restrict__ Wq, const float* __restrict__ Aq, const float* __restrict__ Bq, unsigned short* __restrict__ WqT,
    const float* __restrict__ Wk, const float* __restrict__ Ak, const float* __restrict__ Bk, unsigned short* __restrict__ WkT,
    const float* __restrict__ Wv, const float* __restrict__ Av, const float* __restrict__ Bv, unsigned short* __restrict__ WvT,
    const float* __restrict__ Wo, const float* __restrict__ Ao, const float* __restrict__ Bo, unsigned short* __restrict__ WoT) {
  __shared__ float tile[16][17];
  const int bx = blockIdx.x;
  const float *W, *A, *Bm; unsigned short* WT; int N, nb;
  if (bx < 64)       { W = Wq; A = Aq; Bm = Bq; WT = WqT; N = 1024; nb = bx; }
  else if (bx < 80)  { W = Wk; A = Ak; Bm = Bk; WT = WkT; N = 256;  nb = bx - 64; }
  else if (bx < 96)  { W = Wv; A = Av; Bm = Bv; WT = WvT; N = 256;  nb = bx - 80; }
  else               { W = Wo; A = Ao; Bm = Bo; WT = WoT; N = 1024; nb = bx - 96; }
  const int tx = threadIdx.x, ty = threadIdx.y;
  const int n0 = nb * 16, k0 = blockIdx.y * 16;
  const int n = n0 + tx, k = k0 + ty;
  float acc = W[(size_t)k * N + n];
#pragma unroll
  for (int r = 0; r < 16; ++r) acc += A[k * 16 + r] * Bm[(size_t)r * N + n];
  tile[ty][tx] = acc;
  __syncthreads();
  WT[(size_t)(n0 + ty) * 1024 + (k0 + tx)] = f32_to_bf16(tile[tx][ty]);
}

// ---------- cast f32 -> bf16: query->Xcq, key->Xck, value->Xw ----------
// grid 6144: 2048 blocks per array, 2048 elems per block.
__global__ __launch_bounds__(256) void cast3_kernel(const float* __restrict__ q,
                                                    const float* __restrict__ k,
                                                    const float* __restrict__ v,
                                                    unsigned short* __restrict__ oq,
                                                    unsigned short* __restrict__ ok,
                                                    unsigned short* __restrict__ ov) {
  const int seg = blockIdx.x >> 11;
  const size_t off = ((size_t)(blockIdx.x & 2047) * 256 + threadIdx.x) * 8;
  const float* src = (seg == 0) ? q : (seg == 1) ? k : v;
  unsigned short* dst = (seg == 0) ? oq : (seg == 1) ? ok : ov;
  f32x4 a = *(const f32x4*)(src + off);
  f32x4 b = *(const f32x4*)(src + off + 4);
  *(short8*)(dst + off) = cvt8(a, b);
}

// ---------- m97-style GEMM core: tile 64(M) x 128(N), BK=64, global_load_lds ----------
// 4 waves (2m x 2n); wave computes 32x64 (2x4 frags, 2 k-subtiles = 16 MFMA/step).
// LDS: A[64][64] + B[128][64] bf16 linear (48KB w/ dbuf). Source pre-swizzled
// (chunk ^= row&7), read with same XOR -> 2-way bank alias (free).
// OUTMODE: 0 bf16 row-major; 1 f32 row-major; 2 Vt [(b*4+kv)*64+d][2048];
//          3 K head-major [(b*4+kv)*2048+s][64]
template <int OUTMODE>
DEV void gemm97_core(const unsigned short* __restrict__ X,
                     const unsigned short* __restrict__ WT,
                     void* __restrict__ Cv, int N, int m0b, int n0b,
                     unsigned short* lds) {
  constexpr int K = 1024, BK = 64, NT = K / BK;   // 16 K-steps
  constexpr int ASZ = 64 * 64;                     // 4096 elems (8 KB)
  constexpr int BUFE = ASZ + 128 * 64;             // 12288 elems (24 KB)
  const int tid = threadIdx.x;
  const int w = tid >> 6, l = tid & 63;
  const int lr = l & 15, lg = l >> 4;
  const int wm = w >> 1, wn = w & 1;
  const int srow = l >> 3, schunk = l & 7;         // staging: 8 rows x 8 chunks per instr

  const unsigned short* Xrow0 = X + (size_t)m0b * K;
  const unsigned short* Wrow0 = WT + (size_t)n0b * K;

  f32x4 acc[2][4];
#pragma unroll
  for (int mm = 0; mm < 2; ++mm)
#pragma unroll
    for (int nn = 0; nn < 4; ++nn) acc[mm][nn] = f32x4{0.f, 0.f, 0.f, 0.f};

#define STAGE(T, BUF)                                                        \
  {                                                                          \
    unsigned short* Ab_ = lds + (BUF) * BUFE;                                \
    unsigned short* Bb_ = Ab_ + ASZ;                                         \
    const int k0_ = (T) * BK;                                                \
    _Pragma("unroll")                                                        \
    for (int ii = 0; ii < 2; ++ii) {                                         \
      const int inst_ = 2 * w + ii;                                          \
      const int row_ = inst_ * 8 + srow;                                     \
      const int cs_ = (schunk ^ (row_ & 7)) * 8;                             \
      gld16(Xrow0 + (size_t)row_ * K + k0_ + cs_, Ab_ + inst_ * 512);        \
    }                                                                        \
    _Pragma("unroll")                                                        \
    for (int ii = 0; ii < 4; ++ii) {                                         \
      const int inst_ = 4 * w + ii;                                          \
      const int row_ = inst_ * 8 + srow;                                     \
      const int cs_ = (schunk ^ (row_ & 7)) * 8;                             \
      gld16(Wrow0 + (size_t)row_ * K + k0_ + cs_, Bb_ + inst_ * 512);        \
    }                                                                        \
  }

  STAGE(0, 0)
  __syncthreads();
  int cur = 0;

  for (int t = 0; t < NT; ++t) {
    if (t + 1 < NT) STAGE(t + 1, cur ^ 1)

    const unsigned short* Ab = lds + cur * BUFE;
    const unsigned short* Bb = Ab + ASZ;
    short8 af[2][2], bfg[4][2];
#pragma unroll
    for (int kk = 0; kk < 2; ++kk) {
#pragma unroll
      for (int mm = 0; mm < 2; ++mm) {
        const int row = wm * 32 + mm * 16 + lr;
        const int cc = ((kk * 4 + lg) ^ (row & 7)) * 8;
        af[mm][kk] = *(const short8*)(Ab + row * 64 + cc);
      }
#pragma unroll
      for (int nn = 0; nn < 4; ++nn) {
        const int row = wn * 64 + nn * 16 + lr;
        const int cc = ((kk * 4 + lg) ^ (row & 7)) * 8;
        bfg[nn][kk] = *(const short8*)(Bb + row * 64 + cc);
      }
    }

#pragma unroll
    for (int kk = 0; kk < 2; ++kk)
#pragma unroll
      for (int mm = 0; mm < 2; ++mm)
#pragma unroll
        for (int nn = 0; nn < 4; ++nn)
          acc[mm][nn] = __builtin_amdgcn_mfma_f32_16x16x32_bf16(af[mm][kk], bfg[nn][kk], acc[mm][nn], 0, 0, 0);

    __syncthreads();
    cur ^= 1;
  }
#undef STAGE

#pragma unroll
  for (int mm = 0; mm < 2; ++mm)
#pragma unroll
    for (int nn = 0; nn < 4; ++nn)
#pragma unroll
      for (int i = 0; i < 4; ++i) {
        const int row = m0b + wm * 32 + mm * 16 + lg * 4 + i;
        const int col = n0b + wn * 64 + nn * 16 + lr;
        const float v = acc[mm][nn][i];
        if (OUTMODE == 0) {
          ((unsigned short*)Cv)[(size_t)row * N + col] = f32_to_bf16(v);
        } else if (OUTMODE == 1) {
          ((float*)Cv)[(size_t)row * N + col] = v;
        } else if (OUTMODE == 2) {
          ((unsigned short*)Cv)[((size_t)((row >> 11) * 4 + (col >> 6)) * 64 + (col & 63)) * 2048 + (row & 2047)] = f32_to_bf16(v);
        } else {
          ((unsigned short*)Cv)[((size_t)((row >> 11) * 4 + (col >> 6)) * 2048 + (row & 2047)) * 64 + (col & 63)] = f32_to_bf16(v);
        }
      }
}

// fused Q/K/V projections (bf16 in). Q: 512 blocks (64m x 8n), K/V: 128 each (64m x 2n).
__global__ __launch_bounds__(256, 3) void qkv_kernel(
    const unsigned short* __restrict__ Xq, const unsigned short* __restrict__ Xk, const unsigned short* __restrict__ Xv,
    const unsigned short* __restrict__ WqT, const unsigned short* __restrict__ WkT, const unsigned short* __restrict__ WvT,
    unsigned short* __restrict__ Qw, unsigned short* __restrict__ Khm, unsigned short* __restrict__ Vtw) {
  __shared__ __align__(16) unsigned short lds[2 * (64 * 64 + 128 * 64)];   // 48 KB
  const int bx = blockIdx.x;
  if (bx < 512) {
    const int v = xcd_chunk(bx, 512);
    gemm97_core<0>(Xq, WqT, Qw, 1024, (v >> 3) * 64, (v & 7) * 128, lds);
  } else if (bx < 640) {
    const int v = xcd_chunk(bx - 512, 128);
    gemm97_core<3>(Xk, WkT, Khm, 256, (v >> 1) * 64, (v & 1) * 128, lds);
  } else {
    const int v = xcd_chunk(bx - 640, 128);
    gemm97_core<2>(Xv, WvT, Vtw, 256, (v >> 1) * 64, (v & 1) * 128, lds);
  }
}

// O projection: bf16 in, f32 out. 512 blocks (64m x 8n).
__global__ __launch_bounds__(256, 3) void ogemm_kernel(const unsigned short* __restrict__ Xw,
                                                       const unsigned short* __restrict__ WoT,
                                                       float* __restrict__ out) {
  __shared__ __align__(16) unsigned short lds[2 * (64 * 64 + 128 * 64)];
  const int v = xcd_chunk(blockIdx.x, 512);
  gemm97_core<1>(Xw, WoT, out, 1024, (v >> 3) * 64, (v & 7) * 128, lds);
}

// ---------- flash attention v7 (unchanged): LDS-shared K/V + balanced pairing ----------
__global__ __launch_bounds__(256, 2) void attn7_kernel(const unsigned short* __restrict__ Q,
                                                       const unsigned short* __restrict__ Kh,
                                                       const unsigned short* __restrict__ Vt,
                                                       unsigned short* __restrict__ Xo) {
  __shared__ __align__(16) unsigned short kls[2][64 * 64];
  __shared__ __align__(16) unsigned short vls[2][64 * 64];

  const int tid = threadIdx.x;
  const int l = tid & 63, w = tid >> 6;
  const int cq = l & 31, hi = l >> 5;

  const int bid = blockIdx.x;
  const int half = bid >> 8, p = bid & 255;
  const int h = p & 15, b = (p >> 4) & 1, j = p >> 5;
  const int qt = half ? j : 15 - j;

  const int kv = h >> 2;
  const int qw0 = qt * 128 + w * 32;
  const int q = qw0 + cq;
  const float LOG2E = 1.44269504f;
  const float slope2 = fexp2(-(float)(h + 1)) * LOG2E;
  const float qscale = 0.125f * LOG2E;

  const unsigned short* qp = Q + ((size_t)(b * 2048 + q)) * 1024 + h * 64 + hi * 8;
  short8 qf[4];
#pragma unroll
  for (int c = 0; c < 4; ++c) qf[c] = *(const short8*)(qp + c * 16);

  const int nktb = 2 * qt + 2;
  const int nktw = (qw0 + 31) / 64 + 1;

  const unsigned short* Kg = Kh + (size_t)(b * 4 + kv) * 2048 * 64;
  const unsigned short* Vg = Vt + (size_t)(b * 4 + kv) * 64 * 2048;
  const int j1 = tid, j2 = tid + 256;
  const int rk1 = j1 >> 3, rk2 = j2 >> 3;
  const int kc1 = (j1 & 7) ^ (rk1 & 7), kc2 = (j2 & 7) ^ (rk2 & 7);
  const unsigned short* ksrc1 = Kg + rk1 * 64 + kc1 * 8;
  const unsigned short* ksrc2 = Kg + rk2 * 64 + kc2 * 8;
  const unsigned short* vsrc1 = Vg + (size_t)rk1 * 2048 + kc1 * 8;
  const unsigned short* vsrc2 = Vg + (size_t)rk2 * 2048 + kc2 * 8;

  short8 skr1, skr2, svr1, svr2;
#define STG_LOAD(T)                                                  \
  {                                                                  \
    const int k0_ = (T) * 64;                                        \
    skr1 = *(const short8*)(ksrc1 + k0_ * 64);                       \
    skr2 = *(const short8*)(ksrc2 + k0_ * 64);                       \
    svr1 = *(const short8*)(vsrc1 + k0_);                            \
    svr2 = *(const short8*)(vsrc2 + k0_);                            \
  }
#define STG_WRITE(BUF)                                               \
  {                                                                  \
    *(short8*)(kls[BUF] + j1 * 8) = skr1;                            \
    *(short8*)(kls[BUF] + j2 * 8) = skr2;                            \
    *(short8*)(vls[BUF] + j1 * 8) = svr1;                            \
    *(short8*)(vls[BUF] + j2 * 8) = svr2;                            \
  }

  STG_LOAD(0)
  STG_WRITE(0)
  __syncthreads();
  int cur = 0;

  f32x16 oA, oB;
#pragma unroll
  for (int r = 0; r < 16; ++r) { oA[r] = 0.f; oB[r] = 0.f; }
  float mrun = -3e38f, lrun = 0.f;

  const float fhi = 4.0f * (float)hi;
  const int sx = cq & 7;
  const int rA = cq, rB = cq + 32;

  for (int kt = 0; kt < nktb; ++kt) {
    if (kt + 1 < nktb) STG_LOAD(kt + 1)

    if (kt < nktw) {
      const int k0 = kt * 64;
      const unsigned short* Kl = kls[cur];
      const unsigned short* Vl = vls[cur];

      f32x16 sA, sB;
#pragma unroll
      for (int r = 0; r < 16; ++r) { sA[r] = 0.f; sB[r] = 0.f; }
      __builtin_amdgcn_s_setprio(1);
#pragma unroll
      for (int c = 0; c < 4; ++c) {
        short8 ka = *(const short8*)(Kl + rA * 64 + (((c * 2 + hi) ^ sx) * 8));
        short8 kb = *(const short8*)(Kl + rB * 64 + (((c * 2 + hi) ^ sx) * 8));
        sA = __builtin_amdgcn_mfma_f32_32x32x16_bf16(ka, qf[c], sA, 0, 0, 0);
        sB = __builtin_amdgcn_mfma_f32_32x32x16_bf16(kb, qf[c], sB, 0, 0, 0);
      }
      __builtin_amdgcn_s_setprio(0);

      const float fhb   = fmaf(slope2, fhi, slope2 * (float)(k0 - q));
      const float fhb32 = fmaf(slope2, fhi, slope2 * (float)(k0 + 32 - q));
      const bool masked = (kt == nktw - 1);
      const int ikq4 = k0 - q + 4 * hi;
      float svA[16], svB[16];
#pragma unroll
      for (int r = 0; r < 16; ++r) {
        const int koffc = (r & 3) + 8 * (r >> 2);
        const float kf = (float)koffc;
        float va = fmaf(sA[r], qscale, fmaf(slope2, kf, fhb));
        float vb = fmaf(sB[r], qscale, fmaf(slope2, kf, fhb32));
        if (masked) {
          if (ikq4 + koffc > 0) va = -3e38f;
          if (ikq4 + koffc + 32 > 0) vb = -3e38f;
        }
        svA[r] = va; svB[r] = vb;
      }

      float m0_ = fmaxf(svA[0], svB[0]), m1_ = fmaxf(svA[1], svB[1]);
      float m2_ = fmaxf(svA[2], svB[2]), m3_ = fmaxf(svA[3], svB[3]);
#pragma unroll
      for (int r = 4; r < 16; r += 4) {
        m0_ = fmaxf(m0_, fmaxf(svA[r], svB[r]));
        m1_ = fmaxf(m1_, fmaxf(svA[r + 1], svB[r + 1]));
        m2_ = fmaxf(m2_, fmaxf(svA[r + 2], svB[r + 2]));
        m3_ = fmaxf(m3_, fmaxf(svA[r + 3], svB[r + 3]));
      }
      float mx = fmaxf(fmaxf(m0_, m1_), fmaxf(m2_, m3_));
      mx = fmaxf(mx, __shfl_xor(mx, 32));

      if (!__all(mx <= mrun + 8.0f)) {
        const float mnew = fmaxf(mrun, mx);
        const float fsc = fexp2(mrun - mnew);
        lrun *= fsc;
        mrun = mnew;
#pragma unroll
        for (int r = 0; r < 16; ++r) { oA[r] *= fsc; oB[r] *= fsc; }
      }

      float pA[16], pB[16];
      float l0_ = 0.f, l1_ = 0.f, l2_ = 0.f, l3_ = 0.f;
#pragma unroll
      for (int r = 0; r < 16; r += 4) {
        pA[r] = fexp2(svA[r] - mrun);         pB[r] = fexp2(svB[r] - mrun);
        pA[r + 1] = fexp2(svA[r + 1] - mrun); pB[r + 1] = fexp2(svB[r + 1] - mrun);
        pA[r + 2] = fexp2(svA[r + 2] - mrun); pB[r + 2] = fexp2(svB[r + 2] - mrun);
        pA[r + 3] = fexp2(svA[r + 3] - mrun); pB[r + 3] = fexp2(svB[r + 3] - mrun);
        l0_ += pA[r] + pB[r];
        l1_ += pA[r + 1] + pB[r + 1];
        l2_ += pA[r + 2] + pB[r + 2];
        l3_ += pA[r + 3] + pB[r + 3];
      }
      float ls = (l0_ + l1_) + (l2_ + l3_);
      ls += __shfl_xor(ls, 32);
      lrun += ls;

#define PV_HALF(PARR, KHALF)                                                          \
      {                                                                               \
        _Pragma("unroll")                                                             \
        for (int g = 0; g < 2; ++g) {                                                 \
          unsigned int a0 = cvt_pk_bf16(PARR[g * 8 + 0], PARR[g * 8 + 1]);            \
          unsigned int b0 = cvt_pk_bf16(PARR[g * 8 + 4], PARR[g * 8 + 5]);            \
          unsigned int a1 = cvt_pk_bf16(PARR[g * 8 + 2], PARR[g * 8 + 3]);            \
          unsigned int b1 = cvt_pk_bf16(PARR[g * 8 + 6], PARR[g * 8 + 7]);            \
          uint2v r0 = __builtin_amdgcn_permlane32_swap(a0, b0, false, false);         \
          uint2v r1 = __builtin_amdgcn_permlane32_swap(a1, b1, false, false);         \
          union { unsigned int u[4]; short8 s; } pb_;                                 \
          pb_.u[0] = r0[0]; pb_.u[1] = r1[0]; pb_.u[2] = r0[1]; pb_.u[3] = r1[1];     \
          const int c16 = ((KHALF) * 4 + g * 2 + hi) ^ sx;                            \
          short8 v0 = *(const short8*)(Vl + rA * 64 + c16 * 8);                       \
          short8 v1 = *(const short8*)(Vl + rB * 64 + c16 * 8);                       \
          __builtin_amdgcn_s_setprio(1);                                              \
          oA = __builtin_amdgcn_mfma_f32_32x32x16_bf16(v0, pb_.s, oA, 0, 0, 0);       \
          oB = __builtin_amdgcn_mfma_f32_32x32x16_bf16(v1, pb_.s, oB, 0, 0, 0);       \
          __builtin_amdgcn_s_setprio(0);                                              \
        }                                                                             \
      }
      PV_HALF(pA, 0)
      PV_HALF(pB, 1)
#undef PV_HALF
    }

    if (kt + 1 < nktb) STG_WRITE(cur ^ 1)
    __syncthreads();
    cur ^= 1;
  }
#undef STG_LOAD
#undef STG_WRITE

  const float rinv = __builtin_amdgcn_rcpf(lrun);
  unsigned short* op = Xo + ((size_t)(b * 2048 + q)) * 1024 + h * 64;
#pragma unroll
  for (int g = 0; g < 4; ++g) {
    const int d0 = g * 8 + 4 * hi;
    ushort4v t0, t1;
#pragma unroll
    for (int i = 0; i < 4; ++i) {
      t0[i] = f32_to_bf16(oA[g * 4 + i] * rinv);
      t1[i] = f32_to_bf16(oB[g * 4 + i] * rinv);
    }
    *(ushort4v*)(op + d0) = t0;
    *(ushort4v*)(op + 32 + d0) = t1;
  }
}

extern "C" void kernel_launch(void* const* d_in, const int* in_sizes, int n_in,
                              void* d_out, int out_size, void* d_ws, size_t ws_size,
                              hipStream_t stream) {
  const float* query = (const float*)d_in[0];
  const float* key   = (const float*)d_in[1];
  const float* value = (const float*)d_in[2];
  const float* Wq = (const float*)d_in[3];
  const float* Wk = (const float*)d_in[4];
  const float* Wv = (const float*)d_in[5];
  const float* Wo = (const float*)d_in[6];
  const float* Aq = (const float*)d_in[7];
  const float* Bq = (const float*)d_in[8];
  const float* Ak = (const float*)d_in[9];
  const float* Bk = (const float*)d_in[10];
  const float* Av = (const float*)d_in[11];
  const float* Bv = (const float*)d_in[12];
  const float* Ao = (const float*)d_in[13];
  const float* Bo = (const float*)d_in[14];

  unsigned short* ws  = (unsigned short*)d_ws;
  unsigned short* WqT = ws;                       // 1M elems
  unsigned short* WkT = WqT + 1024 * 1024;        // 256K
  unsigned short* WvT = WkT + 256 * 1024;         // 256K
  unsigned short* WoT = WvT + 256 * 1024;         // 1M
  unsigned short* Qw  = WoT + 1024 * 1024;        // 4M   [B][S][1024]
  unsigned short* Khm = Qw + 4096 * 1024;         // 1M   [(b*4+kv)*2048+s][64]
  unsigned short* Vtw = Khm + 4096 * 256;         // 1M   [(b*4+kv)*64+d][2048]
  unsigned short* Xw  = Vtw + 4096 * 256;         // 4M   value bf16, then attn out
  unsigned short* Xcq = Xw + 4096 * 1024;         // 4M   query bf16
  unsigned short* Xck = Xcq + 4096 * 1024;        // 4M   key bf16   (total 41 MB)

  weff_all_kernel<<<dim3(160, 64), dim3(16, 16), 0, stream>>>(
      Wq, Aq, Bq, WqT, Wk, Ak, Bk, WkT, Wv, Av, Bv, WvT, Wo, Ao, Bo, WoT);

  cast3_kernel<<<6144, 256, 0, stream>>>(query, key, value, Xcq, Xck, Xw);

  qkv_kernel<<<768, 256, 0, stream>>>(Xcq, Xck, Xw, WqT, WkT, WvT, Qw, Khm, Vtw);

  attn7_kernel<<<512, 256, 0, stream>>>(Qw, Khm, Vtw, Xw);

  ogemm_kernel<<<512, 256, 0, stream>>>(Xw, WoT, (float*)d_out);
}

// Round 11
// 101.249 us; speedup vs baseline: 1.8392x; 1.1230x over previous
//
#include <hip/hip_runtime.h>
#include <hip/hip_bf16.h>

// B=2, S=2048, D=1024, H=16, KVH=4, DK=64, R=16, groups=4, SCALING=1.0
// out (f32): (B,S,1024)

typedef __attribute__((ext_vector_type(8))) short short8;
typedef __attribute__((ext_vector_type(4))) float f32x4;
typedef __attribute__((ext_vector_type(16))) float f32x16;
typedef __attribute__((ext_vector_type(2))) unsigned int uint2v;
typedef __attribute__((ext_vector_type(4))) unsigned short ushort4v;

#define DEV static __device__ __forceinline__

DEV unsigned short f32_to_bf16(float f) {
  unsigned int u = __float_as_uint(f);
  u += 0x7FFFu + ((u >> 16) & 1u);   // RNE
  return (unsigned short)(u >> 16);
}

DEV unsigned int cvt_pk_bf16(float lo, float hi) {
  unsigned int r;
  asm("v_cvt_pk_bf16_f32 %0, %1, %2" : "=v"(r) : "v"(lo), "v"(hi));
  return r;
}

DEV float fexp2(float x) { return __builtin_amdgcn_exp2f(x); }

DEV short8 cvt8(f32x4 a, f32x4 b) {
  short8 r;
  r[0] = (short)f32_to_bf16(a[0]); r[1] = (short)f32_to_bf16(a[1]);
  r[2] = (short)f32_to_bf16(a[2]); r[3] = (short)f32_to_bf16(a[3]);
  r[4] = (short)f32_to_bf16(b[0]); r[5] = (short)f32_to_bf16(b[1]);
  r[6] = (short)f32_to_bf16(b[2]); r[7] = (short)f32_to_bf16(b[3]);
  return r;
}

// async global->LDS, 16B per lane; lds base wave-uniform (HW adds lane*16); global src per-lane
DEV void gld16(const unsigned short* g, unsigned short* l) {
  __builtin_amdgcn_global_load_lds(
      (const __attribute__((address_space(1))) void*)g,
      (__attribute__((address_space(3))) void*)l,
      16, 0, 0);
}

// bijective XCD-chunk swizzle (nblk % 8 == 0)
DEV int xcd_chunk(int bid, int nblk) {
  const int chunk = nblk >> 3;
  return (bid & 7) * chunk + (bid >> 3);
}

// ---------- all four W_eff^T in one launch ----------
__global__ __launch_bounds__(256) void weff_all_kernel(
    const float* __restrict__ Wq, const float* __restrict__ Aq, const float* __restrict__ Bq, unsigned short* __restrict__ WqT,
    const float* __restrict__ Wk, const float* __restrict__ Ak, const float* __restrict__ Bk, unsigned short* __restrict__ WkT,
    const float* __restrict__ Wv, const float* __restrict__ Av, const float* __restrict__ Bv, unsigned short* __restrict__ WvT,
    const float* __restrict__ Wo, const float* __restrict__ Ao, const float* __restrict__ Bo, unsigned short* __restrict__ WoT) {
  __shared__ float tile[16][17];
  const int bx = blockIdx.x;
  const float *W, *A, *Bm; unsigned short* WT; int N, nb;
  if (bx < 64)       { W = Wq; A = Aq; Bm = Bq; WT = WqT; N = 1024; nb = bx; }
  else if (bx < 80)  { W = Wk; A = Ak; Bm = Bk; WT = WkT; N = 256;  nb = bx - 64; }
  else if (bx < 96)  { W = Wv; A = Av; Bm = Bv; WT = WvT; N = 256;  nb = bx - 80; }
  else               { W = Wo; A = Ao; Bm = Bo; WT = WoT; N = 1024; nb = bx - 96; }
  const int tx = threadIdx.x, ty = threadIdx.y;
  const int n0 = nb * 16, k0 = blockIdx.y * 16;
  const int n = n0 + tx, k = k0 + ty;
  float acc = W[(size_t)k * N + n];
#pragma unroll
  for (int r = 0; r < 16; ++r) acc += A[k * 16 + r] * Bm[(size_t)r * N + n];
  tile[ty][tx] = acc;
  __syncthreads();
  WT[(size_t)(n0 + ty) * 1024 + (k0 + tx)] = f32_to_bf16(tile[tx][ty]);
}

// ---------- cast f32 -> bf16: query->Xcq, key->Xck, value->Xw ----------
__global__ __launch_bounds__(256) void cast3_kernel(const float* __restrict__ q,
                                                    const float* __restrict__ k,
                                                    const float* __restrict__ v,
                                                    unsigned short* __restrict__ oq,
                                                    unsigned short* __restrict__ ok,
                                                    unsigned short* __restrict__ ov) {
  const int seg = blockIdx.x >> 11;
  const size_t off = ((size_t)(blockIdx.x & 2047) * 256 + threadIdx.x) * 8;
  const float* src = (seg == 0) ? q : (seg == 1) ? k : v;
  unsigned short* dst = (seg == 0) ? oq : (seg == 1) ? ok : ov;
  f32x4 a = *(const f32x4*)(src + off);
  f32x4 b = *(const f32x4*)(src + off + 4);
  *(short8*)(dst + off) = cvt8(a, b);
}

// ---------- m97-style GEMM core (unchanged from round 10) ----------
template <int OUTMODE>
DEV void gemm97_core(const unsigned short* __restrict__ X,
                     const unsigned short* __restrict__ WT,
                     void* __restrict__ Cv, int N, int m0b, int n0b,
                     unsigned short* lds) {
  constexpr int K = 1024, BK = 64, NT = K / BK;
  constexpr int ASZ = 64 * 64;
  constexpr int BUFE = ASZ + 128 * 64;
  const int tid = threadIdx.x;
  const int w = tid >> 6, l = tid & 63;
  const int lr = l & 15, lg = l >> 4;
  const int wm = w >> 1, wn = w & 1;
  const int srow = l >> 3, schunk = l & 7;

  const unsigned short* Xrow0 = X + (size_t)m0b * K;
  const unsigned short* Wrow0 = WT + (size_t)n0b * K;

  f32x4 acc[2][4];
#pragma unroll
  for (int mm = 0; mm < 2; ++mm)
#pragma unroll
    for (int nn = 0; nn < 4; ++nn) acc[mm][nn] = f32x4{0.f, 0.f, 0.f, 0.f};

#define STAGE(T, BUF)                                                        \
  {                                                                          \
    unsigned short* Ab_ = lds + (BUF) * BUFE;                                \
    unsigned short* Bb_ = Ab_ + ASZ;                                         \
    const int k0_ = (T) * BK;                                                \
    _Pragma("unroll")                                                        \
    for (int ii = 0; ii < 2; ++ii) {                                         \
      const int inst_ = 2 * w + ii;                                          \
      const int row_ = inst_ * 8 + srow;                                     \
      const int cs_ = (schunk ^ (row_ & 7)) * 8;                             \
      gld16(Xrow0 + (size_t)row_ * K + k0_ + cs_, Ab_ + inst_ * 512);        \
    }                                                                        \
    _Pragma("unroll")                                                        \
    for (int ii = 0; ii < 4; ++ii) {                                         \
      const int inst_ = 4 * w + ii;                                          \
      const int row_ = inst_ * 8 + srow;                                     \
      const int cs_ = (schunk ^ (row_ & 7)) * 8;                             \
      gld16(Wrow0 + (size_t)row_ * K + k0_ + cs_, Bb_ + inst_ * 512);        \
    }                                                                        \
  }

  STAGE(0, 0)
  __syncthreads();
  int cur = 0;

  for (int t = 0; t < NT; ++t) {
    if (t + 1 < NT) STAGE(t + 1, cur ^ 1)

    const unsigned short* Ab = lds + cur * BUFE;
    const unsigned short* Bb = Ab + ASZ;
    short8 af[2][2], bfg[4][2];
#pragma unroll
    for (int kk = 0; kk < 2; ++kk) {
#pragma unroll
      for (int mm = 0; mm < 2; ++mm) {
        const int row = wm * 32 + mm * 16 + lr;
        const int cc = ((kk * 4 + lg) ^ (row & 7)) * 8;
        af[mm][kk] = *(const short8*)(Ab + row * 64 + cc);
      }
#pragma unroll
      for (int nn = 0; nn < 4; ++nn) {
        const int row = wn * 64 + nn * 16 + lr;
        const int cc = ((kk * 4 + lg) ^ (row & 7)) * 8;
        bfg[nn][kk] = *(const short8*)(Bb + row * 64 + cc);
      }
    }

#pragma unroll
    for (int kk = 0; kk < 2; ++kk)
#pragma unroll
      for (int mm = 0; mm < 2; ++mm)
#pragma unroll
        for (int nn = 0; nn < 4; ++nn)
          acc[mm][nn] = __builtin_amdgcn_mfma_f32_16x16x32_bf16(af[mm][kk], bfg[nn][kk], acc[mm][nn], 0, 0, 0);

    __syncthreads();
    cur ^= 1;
  }
#undef STAGE

#pragma unroll
  for (int mm = 0; mm < 2; ++mm)
#pragma unroll
    for (int nn = 0; nn < 4; ++nn)
#pragma unroll
      for (int i = 0; i < 4; ++i) {
        const int row = m0b + wm * 32 + mm * 16 + lg * 4 + i;
        const int col = n0b + wn * 64 + nn * 16 + lr;
        const float v = acc[mm][nn][i];
        if (OUTMODE == 0) {
          ((unsigned short*)Cv)[(size_t)row * N + col] = f32_to_bf16(v);
        } else if (OUTMODE == 1) {
          ((float*)Cv)[(size_t)row * N + col] = v;
        } else if (OUTMODE == 2) {
          ((unsigned short*)Cv)[((size_t)((row >> 11) * 4 + (col >> 6)) * 64 + (col & 63)) * 2048 + (row & 2047)] = f32_to_bf16(v);
        } else {
          ((unsigned short*)Cv)[((size_t)((row >> 11) * 4 + (col >> 6)) * 2048 + (row & 2047)) * 64 + (col & 63)] = f32_to_bf16(v);
        }
      }
}

__global__ __launch_bounds__(256, 3) void qkv_kernel(
    const unsigned short* __restrict__ Xq, const unsigned short* __restrict__ Xk, const unsigned short* __restrict__ Xv,
    const unsigned short* __restrict__ WqT, const unsigned short* __restrict__ WkT, const unsigned short* __restrict__ WvT,
    unsigned short* __restrict__ Qw, unsigned short* __restrict__ Khm, unsigned short* __restrict__ Vtw) {
  __shared__ __align__(16) unsigned short lds[2 * (64 * 64 + 128 * 64)];   // 48 KB
  const int bx = blockIdx.x;
  if (bx < 512) {
    const int v = xcd_chunk(bx, 512);
    gemm97_core<0>(Xq, WqT, Qw, 1024, (v >> 3) * 64, (v & 7) * 128, lds);
  } else if (bx < 640) {
    const int v = xcd_chunk(bx - 512, 128);
    gemm97_core<3>(Xk, WkT, Khm, 256, (v >> 1) * 64, (v & 1) * 128, lds);
  } else {
    const int v = xcd_chunk(bx - 640, 128);
    gemm97_core<2>(Xv, WvT, Vtw, 256, (v >> 1) * 64, (v & 1) * 128, lds);
  }
}

__global__ __launch_bounds__(256, 3) void ogemm_kernel(const unsigned short* __restrict__ Xw,
                                                       const unsigned short* __restrict__ WoT,
                                                       float* __restrict__ out) {
  __shared__ __align__(16) unsigned short lds[2 * (64 * 64 + 128 * 64)];
  const int v = xcd_chunk(blockIdx.x, 512);
  gemm97_core<1>(Xw, WoT, out, 1024, (v >> 3) * 64, (v & 7) * 128, lds);
}

// ---------- flash attention v8: 8 waves, dual-tile intervals, parity k-split ----------
// grid 512 (balanced pairing), block 512 (8 waves). Wave w: qchunk = w&3 (32 q-rows),
// parity = w>>2. Interval it stages tiles 2it,2it+1 (gld16, pre-swizzled src); parity-p
// wave computes tile 2it+p. Heavy block: 32 tiles -> 16 barrier intervals. End: LDS
// combine of the two k-partials (staging buffer reused).
__global__ __launch_bounds__(512, 4) void attn8_kernel(const unsigned short* __restrict__ Q,
                                                       const unsigned short* __restrict__ Kh,
                                                       const unsigned short* __restrict__ Vt,
                                                       unsigned short* __restrict__ Xo) {
  __shared__ __align__(16) unsigned short sbuf[2][2][2][4096];   // [dbuf][K/V][tile-parity] = 64 KB

  const int tid = threadIdx.x;
  const int l = tid & 63, w = tid >> 6;
  const int cq = l & 31, hi = l >> 5;
  const int qc = w & 3, par = w >> 2;

  const int bid = blockIdx.x;
  const int half = bid >> 8, p = bid & 255;
  const int h = p & 15, b = (p >> 4) & 1, j = p >> 5;
  const int qt = half ? j : 15 - j;                 // complementary pairing: 36 tiles/pair

  const int kv = h >> 2;
  const int qw0 = qt * 128 + qc * 32;
  const int q = qw0 + cq;
  const float LOG2E = 1.44269504f;
  const float slope2 = fexp2(-(float)(h + 1)) * LOG2E;
  const float qscale = 0.125f * LOG2E;

  const unsigned short* qp = Q + ((size_t)(b * 2048 + q)) * 1024 + h * 64 + hi * 8;
  short8 qf[4];
#pragma unroll
  for (int c = 0; c < 4; ++c) qf[c] = *(const short8*)(qp + c * 16);

  const int nit = qt + 1;                    // intervals (2 tiles each)
  const int nktw = (qw0 + 31) / 64 + 1;      // this wave's causal k-tile count

  // staging: thread tid covers chunk tid of each of the 4 tiles (K0,K1,V0,V1).
  // chunk -> row = tid>>3, col16 = (tid&7)^(row&7) (pre-swizzled source, linear dest)
  const unsigned short* Kg = Kh + (size_t)(b * 4 + kv) * 2048 * 64;
  const unsigned short* Vg = Vt + (size_t)(b * 4 + kv) * 64 * 2048;
  const int srow = tid >> 3;
  const int scol = (tid & 7) ^ (srow & 7);
  const unsigned short* ksrc = Kg + srow * 64 + scol * 8;
  const unsigned short* vsrc = Vg + (size_t)srow * 2048 + scol * 8;
  const size_t woff = (size_t)w * 512;       // wave-uniform LDS dest (lane*16B added by HW)

#define STAGE(IT, B_)                                                       \
  {                                                                         \
    const int kb_ = (IT) * 128;                                             \
    gld16(ksrc + (size_t)kb_ * 64,        &sbuf[B_][0][0][woff]);           \
    gld16(ksrc + (size_t)(kb_ + 64) * 64, &sbuf[B_][0][1][woff]);           \
    gld16(vsrc + kb_,                     &sbuf[B_][1][0][woff]);           \
    gld16(vsrc + kb_ + 64,                &sbuf[B_][1][1][woff]);           \
  }

  STAGE(0, 0)
  __syncthreads();
  int cur = 0;

  f32x16 oA, oB;
#pragma unroll
  for (int r = 0; r < 16; ++r) { oA[r] = 0.f; oB[r] = 0.f; }
  float mrun = -3e38f, lrun = 0.f;

  const float fhi = 4.0f * (float)hi;
  const int sx = cq & 7;
  const int rA = cq, rB = cq + 32;

  for (int it = 0; it < nit; ++it) {
    if (it + 1 < nit) STAGE(it + 1, cur ^ 1)

    const int kt = 2 * it + par;
    if (kt < nktw) {
      const int k0 = kt * 64;
      const unsigned short* Kl = &sbuf[cur][0][par][0];
      const unsigned short* Vl = &sbuf[cur][1][par][0];

      f32x16 sA, sB;
#pragma unroll
      for (int r = 0; r < 16; ++r) { sA[r] = 0.f; sB[r] = 0.f; }
      __builtin_amdgcn_s_setprio(1);
#pragma unroll
      for (int c = 0; c < 4; ++c) {
        short8 ka = *(const short8*)(Kl + rA * 64 + (((c * 2 + hi) ^ sx) * 8));
        short8 kb = *(const short8*)(Kl + rB * 64 + (((c * 2 + hi) ^ sx) * 8));
        sA = __builtin_amdgcn_mfma_f32_32x32x16_bf16(ka, qf[c], sA, 0, 0, 0);
        sB = __builtin_amdgcn_mfma_f32_32x32x16_bf16(kb, qf[c], sB, 0, 0, 0);
      }
      __builtin_amdgcn_s_setprio(0);

      const float fhb   = fmaf(slope2, fhi, slope2 * (float)(k0 - q));
      const float fhb32 = fmaf(slope2, fhi, slope2 * (float)(k0 + 32 - q));
      const bool masked = (kt == nktw - 1);
      const int ikq4 = k0 - q + 4 * hi;
      float svA[16], svB[16];
#pragma unroll
      for (int r = 0; r < 16; ++r) {
        const int koffc = (r & 3) + 8 * (r >> 2);
        const float kf = (float)koffc;
        float va = fmaf(sA[r], qscale, fmaf(slope2, kf, fhb));
        float vb = fmaf(sB[r], qscale, fmaf(slope2, kf, fhb32));
        if (masked) {
          if (ikq4 + koffc > 0) va = -3e38f;
          if (ikq4 + koffc + 32 > 0) vb = -3e38f;
        }
        svA[r] = va; svB[r] = vb;
      }

      float m0_ = fmaxf(svA[0], svB[0]), m1_ = fmaxf(svA[1], svB[1]);
      float m2_ = fmaxf(svA[2], svB[2]), m3_ = fmaxf(svA[3], svB[3]);
#pragma unroll
      for (int r = 4; r < 16; r += 4) {
        m0_ = fmaxf(m0_, fmaxf(svA[r], svB[r]));
        m1_ = fmaxf(m1_, fmaxf(svA[r + 1], svB[r + 1]));
        m2_ = fmaxf(m2_, fmaxf(svA[r + 2], svB[r + 2]));
        m3_ = fmaxf(m3_, fmaxf(svA[r + 3], svB[r + 3]));
      }
      float mx = fmaxf(fmaxf(m0_, m1_), fmaxf(m2_, m3_));
      mx = fmaxf(mx, __shfl_xor(mx, 32));

      if (!__all(mx <= mrun + 8.0f)) {
        const float mnew = fmaxf(mrun, mx);
        const float fsc = fexp2(mrun - mnew);
        lrun *= fsc;
        mrun = mnew;
#pragma unroll
        for (int r = 0; r < 16; ++r) { oA[r] *= fsc; oB[r] *= fsc; }
      }

      float pA[16], pB[16];
      float l0_ = 0.f, l1_ = 0.f, l2_ = 0.f, l3_ = 0.f;
#pragma unroll
      for (int r = 0; r < 16; r += 4) {
        pA[r] = fexp2(svA[r] - mrun);         pB[r] = fexp2(svB[r] - mrun);
        pA[r + 1] = fexp2(svA[r + 1] - mrun); pB[r + 1] = fexp2(svB[r + 1] - mrun);
        pA[r + 2] = fexp2(svA[r + 2] - mrun); pB[r + 2] = fexp2(svB[r + 2] - mrun);
        pA[r + 3] = fexp2(svA[r + 3] - mrun); pB[r + 3] = fexp2(svB[r + 3] - mrun);
        l0_ += pA[r] + pB[r];
        l1_ += pA[r + 1] + pB[r + 1];
        l2_ += pA[r + 2] + pB[r + 2];
        l3_ += pA[r + 3] + pB[r + 3];
      }
      float ls = (l0_ + l1_) + (l2_ + l3_);
      ls += __shfl_xor(ls, 32);
      lrun += ls;

#define PV_HALF(PARR, KHALF)                                                          \
      {                                                                               \
        _Pragma("unroll")                                                             \
        for (int g = 0; g < 2; ++g) {                                                 \
          unsigned int a0 = cvt_pk_bf16(PARR[g * 8 + 0], PARR[g * 8 + 1]);            \
          unsigned int b0 = cvt_pk_bf16(PARR[g * 8 + 4], PARR[g * 8 + 5]);            \
          unsigned int a1 = cvt_pk_bf16(PARR[g * 8 + 2], PARR[g * 8 + 3]);            \
          unsigned int b1 = cvt_pk_bf16(PARR[g * 8 + 6], PARR[g * 8 + 7]);            \
          uint2v r0 = __builtin_amdgcn_permlane32_swap(a0, b0, false, false);         \
          uint2v r1 = __builtin_amdgcn_permlane32_swap(a1, b1, false, false);         \
          union { unsigned int u[4]; short8 s; } pb_;                                 \
          pb_.u[0] = r0[0]; pb_.u[1] = r1[0]; pb_.u[2] = r0[1]; pb_.u[3] = r1[1];     \
          const int c16 = ((KHALF) * 4 + g * 2 + hi) ^ sx;                            \
          short8 v0 = *(const short8*)(Vl + rA * 64 + c16 * 8);                       \
          short8 v1 = *(const short8*)(Vl + rB * 64 + c16 * 8);                       \
          __builtin_amdgcn_s_setprio(1);                                              \
          oA = __builtin_amdgcn_mfma_f32_32x32x16_bf16(v0, pb_.s, oA, 0, 0, 0);       \
          oB = __builtin_amdgcn_mfma_f32_32x32x16_bf16(v1, pb_.s, oB, 0, 0, 0);       \
          __builtin_amdgcn_s_setprio(0);                                              \
        }                                                                             \
      }
      PV_HALF(pA, 0)
      PV_HALF(pB, 1)
#undef PV_HALF
    }

    __syncthreads();   // also drains the gld16 staging (compiler emits vmcnt(0))
    cur ^= 1;
  }
#undef STAGE

  // ---- parity combine via reused staging LDS ----
  float* obuf = (float*)&sbuf[0][0][0][0];        // [128][68] f32 = 34816 B
  float* mlb  = obuf + 128 * 68;                  // [128][2]
  const int orow = (qc * 32 + cq) * 68;

  if (par == 1) {
#pragma unroll
    for (int g = 0; g < 4; ++g) {
      f32x4 t0 = {oA[g * 4 + 0], oA[g * 4 + 1], oA[g * 4 + 2], oA[g * 4 + 3]};
      f32x4 t1 = {oB[g * 4 + 0], oB[g * 4 + 1], oB[g * 4 + 2], oB[g * 4 + 3]};
      *(f32x4*)&obuf[orow + g * 8 + 4 * hi] = t0;
      *(f32x4*)&obuf[orow + 32 + g * 8 + 4 * hi] = t1;
    }
    if (hi == 0) {
      mlb[(qc * 32 + cq) * 2] = mrun;
      mlb[(qc * 32 + cq) * 2 + 1] = lrun;
    }
  }
  __syncthreads();
  if (par == 0) {
    const float m1v = mlb[(qc * 32 + cq) * 2];
    const float l1v = mlb[(qc * 32 + cq) * 2 + 1];
    const float ms = fmaxf(mrun, m1v);
    const float s0 = fexp2(mrun - ms), s1 = fexp2(m1v - ms);
    const float rinv = __builtin_amdgcn_rcpf(fmaf(lrun, s0, l1v * s1));
    unsigned short* op = Xo + ((size_t)(b * 2048 + q)) * 1024 + h * 64;
#pragma unroll
    for (int g = 0; g < 4; ++g) {
      const int d0 = g * 8 + 4 * hi;
      f32x4 u0 = *(const f32x4*)&obuf[orow + d0];
      f32x4 u1 = *(const f32x4*)&obuf[orow + 32 + d0];
      ushort4v t0, t1;
#pragma unroll
      for (int i = 0; i < 4; ++i) {
        t0[i] = f32_to_bf16(fmaf(oA[g * 4 + i], s0, u0[i] * s1) * rinv);
        t1[i] = f32_to_bf16(fmaf(oB[g * 4 + i], s0, u1[i] * s1) * rinv);
      }
      *(ushort4v*)(op + d0) = t0;
      *(ushort4v*)(op + 32 + d0) = t1;
    }
  }
}

extern "C" void kernel_launch(void* const* d_in, const int* in_sizes, int n_in,
                              void* d_out, int out_size, void* d_ws, size_t ws_size,
                              hipStream_t stream) {
  const float* query = (const float*)d_in[0];
  const float* key   = (const float*)d_in[1];
  const float* value = (const float*)d_in[2];
  const float* Wq = (const float*)d_in[3];
  const float* Wk = (const float*)d_in[4];
  const float* Wv = (const float*)d_in[5];
  const float* Wo = (const float*)d_in[6];
  const float* Aq = (const float*)d_in[7];
  const float* Bq = (const float*)d_in[8];
  const float* Ak = (const float*)d_in[9];
  const float* Bk = (const float*)d_in[10];
  const float* Av = (const float*)d_in[11];
  const float* Bv = (const float*)d_in[12];
  const float* Ao = (const float*)d_in[13];
  const float* Bo = (const float*)d_in[14];

  unsigned short* ws  = (unsigned short*)d_ws;
  unsigned short* WqT = ws;                       // 1M elems
  unsigned short* WkT = WqT + 1024 * 1024;        // 256K
  unsigned short* WvT = WkT + 256 * 1024;         // 256K
  unsigned short* WoT = WvT + 256 * 1024;         // 1M
  unsigned short* Qw  = WoT + 1024 * 1024;        // 4M   [B][S][1024]
  unsigned short* Khm = Qw + 4096 * 1024;         // 1M   [(b*4+kv)*2048+s][64]
  unsigned short* Vtw = Khm + 4096 * 256;         // 1M   [(b*4+kv)*64+d][2048]
  unsigned short* Xw  = Vtw + 4096 * 256;         // 4M   value bf16, then attn out
  unsigned short* Xcq = Xw + 4096 * 1024;         // 4M   query bf16
  unsigned short* Xck = Xcq + 4096 * 1024;        // 4M   key bf16   (total 41 MB)

  weff_all_kernel<<<dim3(160, 64), dim3(16, 16), 0, stream>>>(
      Wq, Aq, Bq, WqT, Wk, Ak, Bk, WkT, Wv, Av, Bv, WvT, Wo, Ao, Bo, WoT);

  cast3_kernel<<<6144, 256, 0, stream>>>(query, key, value, Xcq, Xck, Xw);

  qkv_kernel<<<768, 256, 0, stream>>>(Xcq, Xck, Xw, WqT, WkT, WvT, Qw, Khm, Vtw);

  attn8_kernel<<<512, 512, 0, stream>>>(Qw, Khm, Vtw, Xw);

  ogemm_kernel<<<512, 256, 0, stream>>>(Xw, WoT, (float*)d_out);
}